// Round 17
// baseline (1915.639 us; speedup 1.0000x reference)
//
#include <hip/hip_runtime.h>
#include <math.h>

// ---------------------------------------------------------------------------
// DETR-style transformer. bf16 MFMA GEMMs (global_load_lds, BK=64 2-phase
// dbuf, XOR-swizzled LDS, XCD-aware block swizzle) + bf16 MFMA flash
// attention (KVBLK=128, NQH q-halves per block, setprio). Split-K GEMMs ->
// f32 partials; k_ln_red fuses reduce+bias+residual+LN+re-add.
// B=4, S=1024, NQ=100, D=512, H=8, dk=64, FF=2048, L=6
// ---------------------------------------------------------------------------

typedef unsigned short bfu;
typedef unsigned int u32;
typedef __bf16 bf8v __attribute__((ext_vector_type(8)));
typedef float f32x4 __attribute__((ext_vector_type(4)));

__device__ inline bfu f2bf(float f) {
  union { float f; u32 u; } v; v.f = f;
  u32 u = v.u;
  u32 r = (u + 0x7fffu + ((u >> 16) & 1u)) >> 16;
  return (bfu)r;
}
__device__ inline float bflo(u32 u) { return __uint_as_float(u << 16); }

typedef const __attribute__((address_space(1))) u32 gas_t;
typedef __attribute__((address_space(3))) u32 las_t;
__device__ __forceinline__ void gl16(const void* g, void* l) {
  __builtin_amdgcn_global_load_lds((gas_t*)g, (las_t*)l, 16, 0, 0);
}

// bijective XCD swizzle (m204): consecutive logical tiles -> same XCD chunk
__device__ __forceinline__ int xcd_swz(int flat, int nwg) {
  int q = nwg >> 3, r = nwg & 7;
  int xcd = flat & 7, idx = flat >> 3;
  return (xcd < r ? xcd * (q + 1) : r * (q + 1) + (xcd - r) * q) + idx;
}

struct GemmLds { bfu As[2][128][64]; bfu Bs[2][128][64]; };      // 64 KB
struct AttnLds { bfu Ks[128][72]; bfu Vt[64][136]; bfu Sm[4][16][136]; };  // 52 KB

// ---------------- device GEMM body: BK=64, gl_lds, 2-phase dbuf ------------
__device__ void dev_gemm(const bfu* __restrict__ A, const bfu* __restrict__ Wt,
                         const float* __restrict__ bias, bfu* __restrict__ C,
                         int M, int N, int K, int relu, int bm, int bn,
                         GemmLds& L) {
  int t = threadIdx.x;
  int wave = t >> 6, lane = t & 63;
  int wm = wave >> 1, wn = wave & 1;
  int l15 = lane & 15, l4 = lane >> 4;
  f32x4 acc[4][4];
  f32x4 zz = {0.f, 0.f, 0.f, 0.f};
#pragma unroll
  for (int mi = 0; mi < 4; ++mi)
#pragma unroll
    for (int ni = 0; ni < 4; ++ni) acc[mi][ni] = zz;

  auto stage = [&](int buf, int k0) {
#pragma unroll
    for (int i = 0; i < 4; ++i) {
      int c = t + i * 256;
      int row = c >> 3, kg = c & 7;
      int sc = kg ^ (row & 7);
      if (bm + row < M)
        gl16(A + (size_t)(bm + row) * K + k0 + sc * 8, &L.As[buf][row][kg * 8]);
      gl16(Wt + (size_t)(bn + row) * K + k0 + sc * 8, &L.Bs[buf][row][kg * 8]);
    }
  };
  stage(0, 0);
  int cur = 0;
  for (int k0 = 0; k0 < K; k0 += 64) {
    __syncthreads();
    if (k0 + 64 < K) stage(cur ^ 1, k0 + 64);
#pragma unroll
    for (int kc = 0; kc < 2; ++kc) {
      bf8v av[4], bv[4];
#pragma unroll
      for (int mi = 0; mi < 4; ++mi) {
        int row = wm * 64 + mi * 16 + l15;
        av[mi] = *(const bf8v*)&L.As[cur][row][((kc * 4 + l4) ^ (row & 7)) * 8];
      }
#pragma unroll
      for (int ni = 0; ni < 4; ++ni) {
        int row = wn * 64 + ni * 16 + l15;
        bv[ni] = *(const bf8v*)&L.Bs[cur][row][((kc * 4 + l4) ^ (row & 7)) * 8];
      }
#pragma unroll
      for (int mi = 0; mi < 4; ++mi)
#pragma unroll
        for (int ni = 0; ni < 4; ++ni)
          acc[mi][ni] = __builtin_amdgcn_mfma_f32_16x16x32_bf16(av[mi], bv[ni],
                                                                acc[mi][ni], 0, 0, 0);
    }
    cur ^= 1;
  }

#pragma unroll
  for (int mi = 0; mi < 4; ++mi) {
    int row0 = bm + wm * 64 + mi * 16 + l4 * 4;
#pragma unroll
    for (int ni = 0; ni < 4; ++ni) {
      int col = bn + wn * 64 + ni * 16 + l15;
      float bb = bias[col];
#pragma unroll
      for (int r = 0; r < 4; ++r) {
        int row = row0 + r;
        if (row < M) {
          float v = acc[mi][ni][r] + bb;
          if (relu) v = fmaxf(v, 0.f);
          C[(size_t)row * N + col] = f2bf(v);
        }
      }
    }
  }
}

// ---------------- device split-K GEMM -> f32 partials ----------------------
__device__ void dev_gemm_sk(const bfu* __restrict__ A, const bfu* __restrict__ Wt,
                            float* __restrict__ Pf, int M, int N, int K,
                            int kbeg, int kend, int bm, int bn, GemmLds& L) {
  int t = threadIdx.x;
  int wave = t >> 6, lane = t & 63;
  int wm = wave >> 1, wn = wave & 1;
  int l15 = lane & 15, l4 = lane >> 4;
  f32x4 acc[4][4];
  f32x4 zz = {0.f, 0.f, 0.f, 0.f};
#pragma unroll
  for (int mi = 0; mi < 4; ++mi)
#pragma unroll
    for (int ni = 0; ni < 4; ++ni) acc[mi][ni] = zz;

  auto stage = [&](int buf, int k0) {
#pragma unroll
    for (int i = 0; i < 4; ++i) {
      int c = t + i * 256;
      int row = c >> 3, kg = c & 7;
      int sc = kg ^ (row & 7);
      if (bm + row < M)
        gl16(A + (size_t)(bm + row) * K + k0 + sc * 8, &L.As[buf][row][kg * 8]);
      gl16(Wt + (size_t)(bn + row) * K + k0 + sc * 8, &L.Bs[buf][row][kg * 8]);
    }
  };
  stage(0, kbeg);
  int cur = 0;
  for (int k0 = kbeg; k0 < kend; k0 += 64) {
    __syncthreads();
    if (k0 + 64 < kend) stage(cur ^ 1, k0 + 64);
#pragma unroll
    for (int kc = 0; kc < 2; ++kc) {
      bf8v av[4], bv[4];
#pragma unroll
      for (int mi = 0; mi < 4; ++mi) {
        int row = wm * 64 + mi * 16 + l15;
        av[mi] = *(const bf8v*)&L.As[cur][row][((kc * 4 + l4) ^ (row & 7)) * 8];
      }
#pragma unroll
      for (int ni = 0; ni < 4; ++ni) {
        int row = wn * 64 + ni * 16 + l15;
        bv[ni] = *(const bf8v*)&L.Bs[cur][row][((kc * 4 + l4) ^ (row & 7)) * 8];
      }
#pragma unroll
      for (int mi = 0; mi < 4; ++mi)
#pragma unroll
        for (int ni = 0; ni < 4; ++ni)
          acc[mi][ni] = __builtin_amdgcn_mfma_f32_16x16x32_bf16(av[mi], bv[ni],
                                                                acc[mi][ni], 0, 0, 0);
    }
    cur ^= 1;
  }

#pragma unroll
  for (int mi = 0; mi < 4; ++mi) {
    int row0 = bm + wm * 64 + mi * 16 + l4 * 4;
#pragma unroll
    for (int ni = 0; ni < 4; ++ni) {
      int col = bn + wn * 64 + ni * 16 + l15;
#pragma unroll
      for (int r = 0; r < 4; ++r) {
        int row = row0 + r;
        if (row < M) Pf[(size_t)row * N + col] = acc[mi][ni][r];
      }
    }
  }
}

// ---------------- device flash attention, KVBLK=128, NQH q-halves ----------
template <int NQH>
__device__ void dev_attn(const bfu* __restrict__ Q, int qs,
                         const bfu* __restrict__ Km,
                         const bfu* __restrict__ Vm, int kvs,
                         bfu* __restrict__ O, int Sq, int Sk,
                         int qblk, int h, int b, AttnLds& L) {
  const float scale = 0.125f;
  int q0 = qblk * (64 * NQH);
  int t = threadIdx.x;
  int wave = t >> 6, lane = t & 63;
  int l15 = lane & 15, l4 = lane >> 4;
  int hoff = h * 64;

  bf8v qf0[NQH], qf1[NQH];
#pragma unroll
  for (int qh = 0; qh < NQH; ++qh) {
    uint4 uq0 = {0u, 0u, 0u, 0u}, uq1 = {0u, 0u, 0u, 0u};
    int qrow = q0 + qh * 64 + wave * 16 + l15;
    if (qrow < Sq) {
      const bfu* qp = Q + (size_t)(b * Sq + qrow) * qs + hoff + l4 * 8;
      uq0 = *(const uint4*)qp;
      uq1 = *(const uint4*)(qp + 32);
    }
    qf0[qh] = *(bf8v*)&uq0;
    qf1[qh] = *(bf8v*)&uq1;
  }

  float m_[NQH][4], l_[NQH][4];
  f32x4 oacc[NQH][4];
  f32x4 zz = {0.f, 0.f, 0.f, 0.f};
#pragma unroll
  for (int qh = 0; qh < NQH; ++qh)
#pragma unroll
    for (int n = 0; n < 4; ++n) {
      m_[qh][n] = -1e30f; l_[qh][n] = 0.f; oacc[qh][n] = zz;
    }

  uint4 ruk[4], ruv[4];
  const uint4 uz = {0u, 0u, 0u, 0u};
  auto load_kv = [&](int k0) {
#pragma unroll
    for (int i = 0; i < 4; ++i) {
      int e = t + i * 256;
      int rk = e >> 3, cg = e & 7;
      ruk[i] = uz;
      if (k0 + rk < Sk)
        ruk[i] = *(const uint4*)(Km + (size_t)(b * Sk + k0 + rk) * kvs + hoff + cg * 8);
      int kv = e & 127, dg = e >> 7;
      ruv[i] = uz;
      if (k0 + kv < Sk)
        ruv[i] = *(const uint4*)(Vm + (size_t)(b * Sk + k0 + kv) * kvs + hoff + dg * 8);
    }
  };
  load_kv(0);

  for (int k0 = 0; k0 < Sk; k0 += 128) {
#pragma unroll
    for (int i = 0; i < 4; ++i) {
      int e = t + i * 256;
      int rk = e >> 3, cg = e & 7;
      *(uint4*)&L.Ks[rk][cg * 8] = ruk[i];
      int kv = e & 127, dg = e >> 7;
      bfu vv[8];
      *(uint4*)vv = ruv[i];
#pragma unroll
      for (int j = 0; j < 8; ++j) L.Vt[dg * 8 + j][kv] = vv[j];
    }
    __syncthreads();
    if (k0 + 128 < Sk) load_kv(k0 + 128);
    bool full = (k0 + 128 <= Sk);

#pragma unroll
    for (int qh = 0; qh < NQH; ++qh) {
      f32x4 s4[8];
      __builtin_amdgcn_s_setprio(1);
#pragma unroll
      for (int tt = 0; tt < 8; ++tt) {
        bf8v kf0 = *(const bf8v*)&L.Ks[tt * 16 + l15][l4 * 8];
        bf8v kf1 = *(const bf8v*)&L.Ks[tt * 16 + l15][32 + l4 * 8];
        f32x4 a = zz;
        a = __builtin_amdgcn_mfma_f32_16x16x32_bf16(qf0[qh], kf0, a, 0, 0, 0);
        a = __builtin_amdgcn_mfma_f32_16x16x32_bf16(qf1[qh], kf1, a, 0, 0, 0);
        s4[tt] = a;
      }
      __builtin_amdgcn_s_setprio(0);

      float f_[4];
#pragma unroll
      for (int r = 0; r < 4; ++r) {
        float sv[8];
        float mx = -1e30f;
        if (full) {
#pragma unroll
          for (int tt = 0; tt < 8; ++tt) {
            float s = s4[tt][r] * scale;
            sv[tt] = s;
            mx = fmaxf(mx, s);
          }
        } else {
#pragma unroll
          for (int tt = 0; tt < 8; ++tt) {
            float s = s4[tt][r] * scale;
            s = (k0 + tt * 16 + l15 < Sk) ? s : -1e30f;
            sv[tt] = s;
            mx = fmaxf(mx, s);
          }
        }
#pragma unroll
        for (int off = 1; off < 16; off <<= 1) mx = fmaxf(mx, __shfl_xor(mx, off));
        float nm = fmaxf(m_[qh][r], mx);
        float f = __expf(m_[qh][r] - nm);
        float ps = 0.f;
#pragma unroll
        for (int tt = 0; tt < 8; ++tt) {
          float p = __expf(sv[tt] - nm);
          ps += p;
          L.Sm[wave][l4 * 4 + r][tt * 16 + l15] = f2bf(p);
        }
#pragma unroll
        for (int off = 1; off < 16; off <<= 1) ps += __shfl_xor(ps, off);
        l_[qh][r] = l_[qh][r] * f + ps;
        m_[qh][r] = nm;
        f_[r] = f;
      }
#pragma unroll
      for (int n = 0; n < 4; ++n)
#pragma unroll
        for (int r = 0; r < 4; ++r) oacc[qh][n][r] *= f_[r];

      __builtin_amdgcn_s_setprio(1);
#pragma unroll
      for (int h2 = 0; h2 < 2; ++h2) {
        bf8v p0 = *(const bf8v*)&L.Sm[wave][l15][h2 * 64 + l4 * 8];
        bf8v p1 = *(const bf8v*)&L.Sm[wave][l15][h2 * 64 + 32 + l4 * 8];
#pragma unroll
        for (int n = 0; n < 4; ++n) {
          bf8v v0 = *(const bf8v*)&L.Vt[n * 16 + l15][h2 * 64 + l4 * 8];
          bf8v v1 = *(const bf8v*)&L.Vt[n * 16 + l15][h2 * 64 + 32 + l4 * 8];
          oacc[qh][n] = __builtin_amdgcn_mfma_f32_16x16x32_bf16(p0, v0, oacc[qh][n], 0, 0, 0);
          oacc[qh][n] = __builtin_amdgcn_mfma_f32_16x16x32_bf16(p1, v1, oacc[qh][n], 0, 0, 0);
        }
      }
      __builtin_amdgcn_s_setprio(0);
    }
    __syncthreads();
  }

#pragma unroll
  for (int qh = 0; qh < NQH; ++qh)
#pragma unroll
    for (int r = 0; r < 4; ++r) {
      int row = q0 + qh * 64 + wave * 16 + l4 * 4 + r;
      if (row < Sq) {
        float inv = 1.f / l_[qh][r];
#pragma unroll
        for (int n = 0; n < 4; ++n)
          O[(size_t)(b * Sq + row) * 512 + hoff + n * 16 + l15] =
              f2bf(oacc[qh][n][r] * inv);
      }
    }
}

// ---------------- device LN(A + sum_z P[z] + bias), fused epilogues --------
__device__ void dev_ln_red(const float* __restrict__ A, const float* __restrict__ P,
                           int nsplit, size_t pz, const float* __restrict__ bias,
                           const float* __restrict__ g, const float* __restrict__ be,
                           float* __restrict__ of, bfu* __restrict__ ob,
                           const float* __restrict__ add2, int qe_mode,
                           float* __restrict__ of2, bfu* __restrict__ ob2,
                           int rows, int tile) {
  int row = tile * 4 + (threadIdx.x >> 6);
  int lane = threadIdx.x & 63;
  if (row < rows) {
    const float* pa = A + (size_t)row * 512;
    float v[8];
    float s = 0.f, s2 = 0.f;
#pragma unroll
    for (int j = 0; j < 8; ++j) {
      int c = lane + j * 64;
      float x = pa[c] + bias[c];
      for (int z = 0; z < nsplit; ++z) x += P[z * pz + (size_t)row * 512 + c];
      v[j] = x; s += x; s2 += x * x;
    }
#pragma unroll
    for (int off = 32; off > 0; off >>= 1) {
      s += __shfl_xor(s, off);
      s2 += __shfl_xor(s2, off);
    }
    float mean = s * (1.f / 512.f);
    float var = s2 * (1.f / 512.f) - mean * mean;
    float r = rsqrtf(var + 1e-5f);
    int arow = qe_mode ? (row % 100) : row;
#pragma unroll
    for (int j = 0; j < 8; ++j) {
      int c = lane + j * 64;
      float o = (v[j] - mean) * r * g[c] + be[c];
      if (of) of[(size_t)row * 512 + c] = o;
      if (ob) ob[(size_t)row * 512 + c] = f2bf(o);
      if (add2) {
        float o2 = o + add2[(size_t)arow * 512 + c];
        if (of2) of2[(size_t)row * 512 + c] = o2;
        if (ob2) ob2[(size_t)row * 512 + c] = f2bf(o2);
      }
    }
  }
}

// ---------------- standalone kernels ----------------------------------------
__global__ __launch_bounds__(256) void k_gemm_bf(const bfu* __restrict__ A,
                                                 const bfu* __restrict__ Wt,
                                                 const float* __restrict__ bias,
                                                 bfu* __restrict__ C,
                                                 int M, int N, int K, int relu,
                                                 size_t wtz, size_t cz, int bz) {
  __shared__ GemmLds L;
  int nwg = gridDim.x * gridDim.y * gridDim.z;
  int flat = blockIdx.x + gridDim.x * (blockIdx.y + gridDim.y * blockIdx.z);
  int s = xcd_swz(flat, nwg);
  int bx = s % gridDim.x; s /= gridDim.x;
  int by = s % gridDim.y;
  int bz2 = s / gridDim.y;
  dev_gemm(A, Wt + (size_t)bz2 * wtz, bias + bz2 * bz, C + (size_t)bz2 * cz,
           M, N, K, relu, by * 128, bx * 128, L);
}

__global__ __launch_bounds__(256) void k_gemm_sk(const bfu* __restrict__ A,
                                                 const bfu* __restrict__ Wt,
                                                 float* __restrict__ Pf,
                                                 int M, int N, int K, int ksplit) {
  __shared__ GemmLds L;
  int nwg = gridDim.x * gridDim.y * gridDim.z;
  int flat = blockIdx.x + gridDim.x * (blockIdx.y + gridDim.y * blockIdx.z);
  int s = xcd_swz(flat, nwg);
  int bx = s % gridDim.x; s /= gridDim.x;
  int by = s % gridDim.y;
  int z = s / gridDim.y;
  int Kc = K / ksplit;
  dev_gemm_sk(A, Wt, Pf + (size_t)z * M * N, M, N, K, z * Kc, z * Kc + Kc,
              by * 128, bx * 128, L);
}

template <int NQH>
__global__ __launch_bounds__(256) void k_attn_mfma(const bfu* __restrict__ Q, int qs,
                                                   const bfu* __restrict__ Km,
                                                   const bfu* __restrict__ Vm, int kvs,
                                                   bfu* __restrict__ O,
                                                   int Sq, int Sk) {
  __shared__ AttnLds L;
  int nwg = gridDim.x * gridDim.y * gridDim.z;
  int flat = blockIdx.x + gridDim.x * (blockIdx.y + gridDim.y * blockIdx.z);
  int s = xcd_swz(flat, nwg);
  int qblk = s % gridDim.x; s /= gridDim.x;
  int h = s % gridDim.y;
  int b = s / gridDim.y;
  dev_attn<NQH>(Q, qs, Km, Vm, kvs, O, Sq, Sk, qblk, h, b, L);
}

__global__ __launch_bounds__(256) void k_ln_red(const float* __restrict__ A,
                                                const float* __restrict__ P,
                                                int nsplit, size_t pz,
                                                const float* __restrict__ bias,
                                                const float* __restrict__ g,
                                                const float* __restrict__ be,
                                                float* __restrict__ of,
                                                bfu* __restrict__ ob,
                                                const float* __restrict__ add2,
                                                int qe_mode,
                                                float* __restrict__ of2,
                                                bfu* __restrict__ ob2,
                                                int rows) {
  dev_ln_red(A, P, nsplit, pz, bias, g, be, of, ob, add2, qe_mode, of2, ob2,
             rows, blockIdx.x);
}

__global__ __launch_bounds__(256) void k_transpose2(const float* __restrict__ s0,
                                                    const float* __restrict__ s1,
                                                    float* __restrict__ d0,
                                                    float* __restrict__ d1) {
  __shared__ float tile[32][33];
  int zz = blockIdx.z;
  const float* in = (zz < 4) ? s0 : s1;
  float* out = (zz < 4) ? d0 : d1;
  int b = zz & 3;
  int c0 = blockIdx.x * 32, s0i = blockIdx.y * 32;
  int tx = threadIdx.x, ty = threadIdx.y;
  for (int i = ty; i < 32; i += 8)
    tile[i][tx] = in[((size_t)(b * 512 + c0 + i)) * 1024 + s0i + tx];
  __syncthreads();
  for (int i = ty; i < 32; i += 8)
    out[((size_t)(b * 1024 + s0i + i)) * 512 + c0 + tx] = tile[tx][i];
}

__global__ __launch_bounds__(256) void k_wt3(const float* __restrict__ s0,
                                             const float* __restrict__ s1,
                                             const float* __restrict__ s2,
                                             bfu* __restrict__ dst,
                                             int K, int N, int per) {
  __shared__ bfu tile[32][33];
  int g = blockIdx.z;
  const float* sb = (g < per) ? s0 : (g < 2 * per) ? s1 : s2;
  int gl = (g < per) ? g : (g < 2 * per) ? (g - per) : (g - 2 * per);
  const float* s = sb + (size_t)gl * (size_t)K * N;
  bfu* d = dst + (size_t)g * (size_t)K * N;
  int n0 = blockIdx.x * 32, k0 = blockIdx.y * 32;
  int tx = threadIdx.x, ty = threadIdx.y;
  for (int i = ty; i < 32; i += 8)
    tile[i][tx] = f2bf(s[(size_t)(k0 + i) * N + n0 + tx]);
  __syncthreads();
  for (int i = ty; i < 32; i += 8)
    d[(size_t)(n0 + i) * K + k0 + tx] = tile[tx][i];
}

__global__ void k_add_dual(const float* __restrict__ a, const float* __restrict__ b,
                           float* __restrict__ of, bfu* __restrict__ ob, int n4) {
  int i = blockIdx.x * blockDim.x + threadIdx.x;
  if (i >= n4) return;
  float4 x = ((const float4*)a)[i];
  float4 y = ((const float4*)b)[i];
  float4 r = make_float4(x.x + y.x, x.y + y.y, x.z + y.z, x.w + y.w);
  ((float4*)of)[i] = r;
  ((ushort4*)ob)[i] = make_ushort4(f2bf(r.x), f2bf(r.y), f2bf(r.z), f2bf(r.w));
}

__global__ void k_qe0(const float* __restrict__ qe, float* __restrict__ of,
                      bfu* __restrict__ ob) {
  int i = blockIdx.x * blockDim.x + threadIdx.x;
  if (i >= 51200) return;
  int row = i >> 7;
  int q = row % 100;
  int c4 = i & 127;
  float4 y = ((const float4*)qe)[q * 128 + c4];
  ((float4*)of)[i] = y;
  ((ushort4*)ob)[i] = make_ushort4(f2bf(y.x), f2bf(y.y), f2bf(y.z), f2bf(y.w));
}

// ---------------------------------------------------------------------------

extern "C" void kernel_launch(void* const* d_in, const int* in_sizes, int n_in,
                              void* d_out, int out_size, void* d_ws, size_t ws_size,
                              hipStream_t stream) {
  const float* src         = (const float*)d_in[0];
  const float* query_embed = (const float*)d_in[1];
  const float* pos_embed   = (const float*)d_in[2];
  const float* enc_attn_w  = (const float*)d_in[3];
  const float* enc_attn_b  = (const float*)d_in[4];
  const float* enc_w1      = (const float*)d_in[5];
  const float* enc_b1      = (const float*)d_in[6];
  const float* enc_w2      = (const float*)d_in[7];
  const float* enc_b2      = (const float*)d_in[8];
  const float* enc_ln_w    = (const float*)d_in[9];
  const float* enc_ln_b    = (const float*)d_in[10];
  const float* dec_sa_w    = (const float*)d_in[11];
  const float* dec_sa_b    = (const float*)d_in[12];
  const float* dec_ca_w    = (const float*)d_in[13];
  const float* dec_ca_b    = (const float*)d_in[14];
  const float* dec_w1      = (const float*)d_in[15];
  const float* dec_b1      = (const float*)d_in[16];
  const float* dec_w2      = (const float*)d_in[17];
  const float* dec_b2      = (const float*)d_in[18];
  const float* dec_ln_w    = (const float*)d_in[19];
  const float* dec_ln_b    = (const float*)d_in[20];
  float* out = (float*)d_out;

  const size_t ENC = 4UL * 1024 * 512;
  const size_t DEC = 4UL * 100 * 512;
  const size_t MAT = 512UL * 512;

  float* p = (float*)d_ws;
  float* x    = p; p += ENC;
  float* pos  = p; p += ENC;
  float* t1   = p; p += ENC;
  float* t2   = p; p += ENC;
  float* t3   = p; p += DEC;
  float* Pf   = p; p += 4 * ENC;   // split-K f32 partials

  bfu* bp = (bfu*)p;
  bfu* t1b    = bp; bp += ENC;
  bfu* t2b    = bp; bp += ENC;
  bfu* t3b    = bp; bp += DEC;
  bfu* qkvb   = bp; bp += 4096UL * 1536;
  bfu* aob    = bp; bp += ENC;
  bfu* hbb    = bp; bp += 4096UL * 2048;
  bfu* meminb = bp; bp += ENC;
  bfu* ckvb   = bp; bp += 6UL * 4096 * 1024;
  bfu* att_all_t = bp; bp += 72 * MAT;
  bfu* w1_all_t  = bp; bp += 12UL * 512 * 2048;
  bfu* w2_all_t  = bp; bp += 12UL * 2048 * 512;
  bfu* enc_att_t = att_all_t;
  bfu* dsa_t     = att_all_t + 24 * MAT;
  bfu* dca_t     = att_all_t + 48 * MAT;
  bfu* enc_w1t   = w1_all_t;
  bfu* dw1t      = w1_all_t + 6UL * 512 * 2048;
  bfu* enc_w2t   = w2_all_t;
  bfu* dw2t      = w2_all_t + 6UL * 2048 * 512;

  dim3 tb(32, 8);
  k_transpose2<<<dim3(16, 32, 8), tb, 0, stream>>>(src, pos_embed, x, pos);

  k_wt3<<<dim3(16, 16, 72), tb, 0, stream>>>(enc_attn_w, dec_sa_w, dec_ca_w,
                                             att_all_t, 512, 512, 24);
  k_wt3<<<dim3(64, 16, 12), tb, 0, stream>>>(enc_w1, dec_w1, dec_w1,
                                             w1_all_t, 512, 2048, 6);
  k_wt3<<<dim3(16, 64, 12), tb, 0, stream>>>(enc_w2, dec_w2, dec_w2,
                                             w2_all_t, 2048, 512, 6);

  // ----------------------------- encoder ----------------------------------
  k_add_dual<<<2048, 256, 0, stream>>>(x, pos, t1, t1b, (int)(ENC / 4));
  for (int l = 0; l < 6; ++l) {
    const bfu* awt = enc_att_t + (size_t)l * 4 * MAT;
    const float* ab = enc_attn_b + (size_t)l * 2048;
    k_gemm_bf<<<dim3(12, 32), 256, 0, stream>>>(t1b, awt, ab,
                                                qkvb, 4096, 1536, 512, 0, 0, 0, 0);
    k_attn_mfma<2><<<dim3(8, 8, 4), 256, 0, stream>>>(qkvb, 1536, qkvb + 512,
                                                      qkvb + 1024, 1536,
                                                      aob, 1024, 1024);
    k_gemm_sk<<<dim3(4, 32, 2), 256, 0, stream>>>(aob, awt + 3 * MAT, Pf,
                                                  4096, 512, 512, 2);
    k_ln_red<<<1024, 256, 0, stream>>>(t1, Pf, 2, ENC, ab + 1536,
                                       enc_ln_w + (size_t)(l * 2 + 0) * 512,
                                       enc_ln_b + (size_t)(l * 2 + 0) * 512,
                                       t2, t2b, (const float*)nullptr, 0,
                                       (float*)nullptr, (bfu*)nullptr, 4096);
    k_gemm_bf<<<dim3(16, 32), 256, 0, stream>>>(t2b, enc_w1t + (size_t)l * 512 * 2048,
                                                enc_b1 + (size_t)l * 2048, hbb,
                                                4096, 2048, 512, 1, 0, 0, 0);
    k_gemm_sk<<<dim3(4, 32, 4), 256, 0, stream>>>(hbb, enc_w2t + (size_t)l * 2048 * 512, Pf,
                                                  4096, 512, 2048, 4);
    if (l < 5) {
      k_ln_red<<<1024, 256, 0, stream>>>(t2, Pf, 4, ENC, enc_b2 + (size_t)l * 512,
                                         enc_ln_w + (size_t)(l * 2 + 1) * 512,
                                         enc_ln_b + (size_t)(l * 2 + 1) * 512,
                                         (float*)nullptr, (bfu*)nullptr,
                                         pos, 0, t1, t1b, 4096);
    } else {
      k_ln_red<<<1024, 256, 0, stream>>>(t2, Pf, 4, ENC, enc_b2 + (size_t)l * 512,
                                         enc_ln_w + (size_t)(l * 2 + 1) * 512,
                                         enc_ln_b + (size_t)(l * 2 + 1) * 512,
                                         out + DEC, (bfu*)nullptr,
                                         pos, 0, (float*)nullptr, meminb, 4096);
    }
  }

  // all 6 decoder layers' cross-attn K/V projections in one dispatch
  k_gemm_bf<<<dim3(8, 32, 6), 256, 0, stream>>>(meminb, dca_t + MAT, dec_ca_b + 512,
                                                ckvb, 4096, 1024, 512, 0,
                                                4 * MAT, 4096UL * 1024, 2048);

  // ----------------------------- decoder ----------------------------------
  k_qe0<<<200, 256, 0, stream>>>(query_embed, t1, t1b);
  for (int l = 0; l < 6; ++l) {
    const bfu* swt = dsa_t + (size_t)l * 4 * MAT;
    const bfu* cwt = dca_t + (size_t)l * 4 * MAT;
    const float* sb = dec_sa_b + (size_t)l * 2048;
    const float* cb = dec_ca_b + (size_t)l * 2048;
    // self-attention
    k_gemm_bf<<<dim3(12, 4), 256, 0, stream>>>(t1b, swt, sb,
                                               qkvb, 400, 1536, 512, 0, 0, 0, 0);
    k_attn_mfma<1><<<dim3(2, 8, 4), 256, 0, stream>>>(qkvb, 1536, qkvb + 512,
                                                      qkvb + 1024, 1536,
                                                      aob, 100, 100);
    k_gemm_sk<<<dim3(4, 4, 2), 256, 0, stream>>>(aob, swt + 3 * MAT, Pf,
                                                 400, 512, 512, 2);
    k_ln_red<<<100, 256, 0, stream>>>(t1, Pf, 2, 400UL * 512, sb + 1536,
                                      dec_ln_w + (size_t)(l * 3 + 0) * 512,
                                      dec_ln_b + (size_t)(l * 3 + 0) * 512,
                                      t2, t2b, (const float*)nullptr, 0,
                                      (float*)nullptr, (bfu*)nullptr, 400);
    // cross-attention
    k_gemm_bf<<<dim3(4, 4), 256, 0, stream>>>(t2b, cwt, cb,
                                              qkvb, 400, 512, 512, 0, 0, 0, 0);
    k_attn_mfma<1><<<dim3(2, 8, 4), 256, 0, stream>>>(qkvb, 512,
                                                      ckvb + (size_t)l * 4096 * 1024,
                                                      ckvb + (size_t)l * 4096 * 1024 + 512,
                                                      1024, aob, 100, 1024);
    k_gemm_sk<<<dim3(4, 4, 2), 256, 0, stream>>>(aob, cwt + 3 * MAT, Pf,
                                                 400, 512, 512, 2);
    k_ln_red<<<100, 256, 0, stream>>>(t2, Pf, 2, 400UL * 512, cb + 1536,
                                      dec_ln_w + (size_t)(l * 3 + 1) * 512,
                                      dec_ln_b + (size_t)(l * 3 + 1) * 512,
                                      t3, t3b, (const float*)nullptr, 0,
                                      (float*)nullptr, (bfu*)nullptr, 400);
    // ffn
    k_gemm_bf<<<dim3(16, 4), 256, 0, stream>>>(t3b, dw1t + (size_t)l * 512 * 2048,
                                               dec_b1 + (size_t)l * 2048, hbb,
                                               400, 2048, 512, 1, 0, 0, 0);
    k_gemm_sk<<<dim3(4, 4, 4), 256, 0, stream>>>(hbb, dw2t + (size_t)l * 2048 * 512, Pf,
                                                 400, 512, 2048, 4);
    if (l < 5) {
      k_ln_red<<<100, 256, 0, stream>>>(t3, Pf, 4, 400UL * 512, dec_b2 + (size_t)l * 512,
                                        dec_ln_w + (size_t)(l * 3 + 2) * 512,
                                        dec_ln_b + (size_t)(l * 3 + 2) * 512,
                                        (float*)nullptr, (bfu*)nullptr,
                                        query_embed, 1, t1, t1b, 400);
    } else {
      k_ln_red<<<100, 256, 0, stream>>>(t3, Pf, 4, 400UL * 512, dec_b2 + (size_t)l * 512,
                                        dec_ln_w + (size_t)(l * 3 + 2) * 512,
                                        dec_ln_b + (size_t)(l * 3 + 2) * 512,
                                        out, (bfu*)nullptr, (const float*)nullptr, 0,
                                        (float*)nullptr, (bfu*)nullptr, 400);
    }
  }
}

// Round 18
// 1852.278 us; speedup vs baseline: 1.0342x; 1.0342x over previous
//
#include <hip/hip_runtime.h>
#include <math.h>

// ---------------------------------------------------------------------------
// DETR-style transformer. bf16 MFMA GEMMs (global_load_lds, BK=64 2-phase
// dbuf, XOR-swizzled LDS, XCD-aware block swizzle on GEMM + attention) +
// bf16 MFMA flash attention (KVBLK=128, setprio). Split-K GEMMs -> f32
// partials; k_ln_red fuses reduce+bias+residual+LN+re-add.
// B=4, S=1024, NQ=100, D=512, H=8, dk=64, FF=2048, L=6
// ---------------------------------------------------------------------------

typedef unsigned short bfu;
typedef unsigned int u32;
typedef __bf16 bf8v __attribute__((ext_vector_type(8)));
typedef float f32x4 __attribute__((ext_vector_type(4)));

__device__ inline bfu f2bf(float f) {
  union { float f; u32 u; } v; v.f = f;
  u32 u = v.u;
  u32 r = (u + 0x7fffu + ((u >> 16) & 1u)) >> 16;
  return (bfu)r;
}
__device__ inline float bflo(u32 u) { return __uint_as_float(u << 16); }

typedef const __attribute__((address_space(1))) u32 gas_t;
typedef __attribute__((address_space(3))) u32 las_t;
__device__ __forceinline__ void gl16(const void* g, void* l) {
  __builtin_amdgcn_global_load_lds((gas_t*)g, (las_t*)l, 16, 0, 0);
}

// bijective XCD swizzle (m204): consecutive logical tiles -> same XCD chunk
__device__ __forceinline__ int xcd_swz(int flat, int nwg) {
  int q = nwg >> 3, r = nwg & 7;
  int xcd = flat & 7, idx = flat >> 3;
  return (xcd < r ? xcd * (q + 1) : r * (q + 1) + (xcd - r) * q) + idx;
}

struct GemmLds { bfu As[2][128][64]; bfu Bs[2][128][64]; };      // 64 KB
struct AttnLds { bfu Ks[128][72]; bfu Vt[64][136]; bfu Sm[4][16][136]; };  // 52 KB

// ---------------- device GEMM body: BK=64, gl_lds, 2-phase dbuf ------------
__device__ void dev_gemm(const bfu* __restrict__ A, const bfu* __restrict__ Wt,
                         const float* __restrict__ bias, bfu* __restrict__ C,
                         int M, int N, int K, int relu, int bm, int bn,
                         GemmLds& L) {
  int t = threadIdx.x;
  int wave = t >> 6, lane = t & 63;
  int wm = wave >> 1, wn = wave & 1;
  int l15 = lane & 15, l4 = lane >> 4;
  f32x4 acc[4][4];
  f32x4 zz = {0.f, 0.f, 0.f, 0.f};
#pragma unroll
  for (int mi = 0; mi < 4; ++mi)
#pragma unroll
    for (int ni = 0; ni < 4; ++ni) acc[mi][ni] = zz;

  auto stage = [&](int buf, int k0) {
#pragma unroll
    for (int i = 0; i < 4; ++i) {
      int c = t + i * 256;
      int row = c >> 3, kg = c & 7;
      int sc = kg ^ (row & 7);
      if (bm + row < M)
        gl16(A + (size_t)(bm + row) * K + k0 + sc * 8, &L.As[buf][row][kg * 8]);
      gl16(Wt + (size_t)(bn + row) * K + k0 + sc * 8, &L.Bs[buf][row][kg * 8]);
    }
  };
  stage(0, 0);
  int cur = 0;
  for (int k0 = 0; k0 < K; k0 += 64) {
    __syncthreads();
    if (k0 + 64 < K) stage(cur ^ 1, k0 + 64);
#pragma unroll
    for (int kc = 0; kc < 2; ++kc) {
      bf8v av[4], bv[4];
#pragma unroll
      for (int mi = 0; mi < 4; ++mi) {
        int row = wm * 64 + mi * 16 + l15;
        av[mi] = *(const bf8v*)&L.As[cur][row][((kc * 4 + l4) ^ (row & 7)) * 8];
      }
#pragma unroll
      for (int ni = 0; ni < 4; ++ni) {
        int row = wn * 64 + ni * 16 + l15;
        bv[ni] = *(const bf8v*)&L.Bs[cur][row][((kc * 4 + l4) ^ (row & 7)) * 8];
      }
#pragma unroll
      for (int mi = 0; mi < 4; ++mi)
#pragma unroll
        for (int ni = 0; ni < 4; ++ni)
          acc[mi][ni] = __builtin_amdgcn_mfma_f32_16x16x32_bf16(av[mi], bv[ni],
                                                                acc[mi][ni], 0, 0, 0);
    }
    cur ^= 1;
  }

#pragma unroll
  for (int mi = 0; mi < 4; ++mi) {
    int row0 = bm + wm * 64 + mi * 16 + l4 * 4;
#pragma unroll
    for (int ni = 0; ni < 4; ++ni) {
      int col = bn + wn * 64 + ni * 16 + l15;
      float bb = bias[col];
#pragma unroll
      for (int r = 0; r < 4; ++r) {
        int row = row0 + r;
        if (row < M) {
          float v = acc[mi][ni][r] + bb;
          if (relu) v = fmaxf(v, 0.f);
          C[(size_t)row * N + col] = f2bf(v);
        }
      }
    }
  }
}

// ---------------- device split-K GEMM -> f32 partials ----------------------
__device__ void dev_gemm_sk(const bfu* __restrict__ A, const bfu* __restrict__ Wt,
                            float* __restrict__ Pf, int M, int N, int K,
                            int kbeg, int kend, int bm, int bn, GemmLds& L) {
  int t = threadIdx.x;
  int wave = t >> 6, lane = t & 63;
  int wm = wave >> 1, wn = wave & 1;
  int l15 = lane & 15, l4 = lane >> 4;
  f32x4 acc[4][4];
  f32x4 zz = {0.f, 0.f, 0.f, 0.f};
#pragma unroll
  for (int mi = 0; mi < 4; ++mi)
#pragma unroll
    for (int ni = 0; ni < 4; ++ni) acc[mi][ni] = zz;

  auto stage = [&](int buf, int k0) {
#pragma unroll
    for (int i = 0; i < 4; ++i) {
      int c = t + i * 256;
      int row = c >> 3, kg = c & 7;
      int sc = kg ^ (row & 7);
      if (bm + row < M)
        gl16(A + (size_t)(bm + row) * K + k0 + sc * 8, &L.As[buf][row][kg * 8]);
      gl16(Wt + (size_t)(bn + row) * K + k0 + sc * 8, &L.Bs[buf][row][kg * 8]);
    }
  };
  stage(0, kbeg);
  int cur = 0;
  for (int k0 = kbeg; k0 < kend; k0 += 64) {
    __syncthreads();
    if (k0 + 64 < kend) stage(cur ^ 1, k0 + 64);
#pragma unroll
    for (int kc = 0; kc < 2; ++kc) {
      bf8v av[4], bv[4];
#pragma unroll
      for (int mi = 0; mi < 4; ++mi) {
        int row = wm * 64 + mi * 16 + l15;
        av[mi] = *(const bf8v*)&L.As[cur][row][((kc * 4 + l4) ^ (row & 7)) * 8];
      }
#pragma unroll
      for (int ni = 0; ni < 4; ++ni) {
        int row = wn * 64 + ni * 16 + l15;
        bv[ni] = *(const bf8v*)&L.Bs[cur][row][((kc * 4 + l4) ^ (row & 7)) * 8];
      }
#pragma unroll
      for (int mi = 0; mi < 4; ++mi)
#pragma unroll
        for (int ni = 0; ni < 4; ++ni)
          acc[mi][ni] = __builtin_amdgcn_mfma_f32_16x16x32_bf16(av[mi], bv[ni],
                                                                acc[mi][ni], 0, 0, 0);
    }
    cur ^= 1;
  }

#pragma unroll
  for (int mi = 0; mi < 4; ++mi) {
    int row0 = bm + wm * 64 + mi * 16 + l4 * 4;
#pragma unroll
    for (int ni = 0; ni < 4; ++ni) {
      int col = bn + wn * 64 + ni * 16 + l15;
#pragma unroll
      for (int r = 0; r < 4; ++r) {
        int row = row0 + r;
        if (row < M) Pf[(size_t)row * N + col] = acc[mi][ni][r];
      }
    }
  }
}

// ---------------- device flash attention, KVBLK=128 ------------------------
__device__ void dev_attn(const bfu* __restrict__ Q, int qs,
                         const bfu* __restrict__ Km,
                         const bfu* __restrict__ Vm, int kvs,
                         bfu* __restrict__ O, int Sq, int Sk,
                         int qblk, int h, int b, AttnLds& L) {
  const float scale = 0.125f;
  int q0 = qblk * 64;
  int t = threadIdx.x;
  int wave = t >> 6, lane = t & 63;
  int l15 = lane & 15, l4 = lane >> 4;
  int hoff = h * 64;

  uint4 uq0 = {0u, 0u, 0u, 0u}, uq1 = {0u, 0u, 0u, 0u};
  {
    int qrow = q0 + wave * 16 + l15;
    if (qrow < Sq) {
      const bfu* qp = Q + (size_t)(b * Sq + qrow) * qs + hoff + l4 * 8;
      uq0 = *(const uint4*)qp;
      uq1 = *(const uint4*)(qp + 32);
    }
  }
  bf8v qf0 = *(bf8v*)&uq0, qf1 = *(bf8v*)&uq1;

  float m_[4] = {-1e30f, -1e30f, -1e30f, -1e30f};
  float l_[4] = {0.f, 0.f, 0.f, 0.f};
  f32x4 oacc[4];
  f32x4 zz = {0.f, 0.f, 0.f, 0.f};
#pragma unroll
  for (int n = 0; n < 4; ++n) oacc[n] = zz;

  uint4 ruk[4], ruv[4];
  const uint4 uz = {0u, 0u, 0u, 0u};
  auto load_kv = [&](int k0) {
#pragma unroll
    for (int i = 0; i < 4; ++i) {
      int e = t + i * 256;
      int rk = e >> 3, cg = e & 7;
      ruk[i] = uz;
      if (k0 + rk < Sk)
        ruk[i] = *(const uint4*)(Km + (size_t)(b * Sk + k0 + rk) * kvs + hoff + cg * 8);
      int kv = e & 127, dg = e >> 7;
      ruv[i] = uz;
      if (k0 + kv < Sk)
        ruv[i] = *(const uint4*)(Vm + (size_t)(b * Sk + k0 + kv) * kvs + hoff + dg * 8);
    }
  };
  load_kv(0);

  for (int k0 = 0; k0 < Sk; k0 += 128) {
#pragma unroll
    for (int i = 0; i < 4; ++i) {
      int e = t + i * 256;
      int rk = e >> 3, cg = e & 7;
      *(uint4*)&L.Ks[rk][cg * 8] = ruk[i];
      int kv = e & 127, dg = e >> 7;
      bfu vv[8];
      *(uint4*)vv = ruv[i];
#pragma unroll
      for (int j = 0; j < 8; ++j) L.Vt[dg * 8 + j][kv] = vv[j];
    }
    __syncthreads();
    if (k0 + 128 < Sk) load_kv(k0 + 128);

    f32x4 s4[8];
    __builtin_amdgcn_s_setprio(1);
#pragma unroll
    for (int tt = 0; tt < 8; ++tt) {
      bf8v kf0 = *(const bf8v*)&L.Ks[tt * 16 + l15][l4 * 8];
      bf8v kf1 = *(const bf8v*)&L.Ks[tt * 16 + l15][32 + l4 * 8];
      f32x4 a = zz;
      a = __builtin_amdgcn_mfma_f32_16x16x32_bf16(qf0, kf0, a, 0, 0, 0);
      a = __builtin_amdgcn_mfma_f32_16x16x32_bf16(qf1, kf1, a, 0, 0, 0);
      s4[tt] = a;
    }
    __builtin_amdgcn_s_setprio(0);

    bool full = (k0 + 128 <= Sk);
    float f_[4];
#pragma unroll
    for (int r = 0; r < 4; ++r) {
      float sv[8];
      float mx = -1e30f;
      if (full) {
#pragma unroll
        for (int tt = 0; tt < 8; ++tt) {
          float s = s4[tt][r] * scale;
          sv[tt] = s;
          mx = fmaxf(mx, s);
        }
      } else {
#pragma unroll
        for (int tt = 0; tt < 8; ++tt) {
          float s = s4[tt][r] * scale;
          s = (k0 + tt * 16 + l15 < Sk) ? s : -1e30f;
          sv[tt] = s;
          mx = fmaxf(mx, s);
        }
      }
#pragma unroll
      for (int off = 1; off < 16; off <<= 1) mx = fmaxf(mx, __shfl_xor(mx, off));
      float nm = fmaxf(m_[r], mx);
      float f = __expf(m_[r] - nm);
      float ps = 0.f;
#pragma unroll
      for (int tt = 0; tt < 8; ++tt) {
        float p = __expf(sv[tt] - nm);
        ps += p;
        L.Sm[wave][l4 * 4 + r][tt * 16 + l15] = f2bf(p);
      }
#pragma unroll
      for (int off = 1; off < 16; off <<= 1) ps += __shfl_xor(ps, off);
      l_[r] = l_[r] * f + ps;
      m_[r] = nm;
      f_[r] = f;
    }
#pragma unroll
    for (int n = 0; n < 4; ++n)
#pragma unroll
      for (int r = 0; r < 4; ++r) oacc[n][r] *= f_[r];

    __builtin_amdgcn_s_setprio(1);
#pragma unroll
    for (int h2 = 0; h2 < 2; ++h2) {
      bf8v p0 = *(const bf8v*)&L.Sm[wave][l15][h2 * 64 + l4 * 8];
      bf8v p1 = *(const bf8v*)&L.Sm[wave][l15][h2 * 64 + 32 + l4 * 8];
#pragma unroll
      for (int n = 0; n < 4; ++n) {
        bf8v v0 = *(const bf8v*)&L.Vt[n * 16 + l15][h2 * 64 + l4 * 8];
        bf8v v1 = *(const bf8v*)&L.Vt[n * 16 + l15][h2 * 64 + 32 + l4 * 8];
        oacc[n] = __builtin_amdgcn_mfma_f32_16x16x32_bf16(p0, v0, oacc[n], 0, 0, 0);
        oacc[n] = __builtin_amdgcn_mfma_f32_16x16x32_bf16(p1, v1, oacc[n], 0, 0, 0);
      }
    }
    __builtin_amdgcn_s_setprio(0);
    __syncthreads();
  }

#pragma unroll
  for (int r = 0; r < 4; ++r) {
    int row = q0 + wave * 16 + l4 * 4 + r;
    if (row < Sq) {
      float inv = 1.f / l_[r];
#pragma unroll
      for (int n = 0; n < 4; ++n)
        O[(size_t)(b * Sq + row) * 512 + hoff + n * 16 + l15] = f2bf(oacc[n][r] * inv);
    }
  }
}

// ---------------- device LN(A + sum_z P[z] + bias), fused epilogues --------
__device__ void dev_ln_red(const float* __restrict__ A, const float* __restrict__ P,
                           int nsplit, size_t pz, const float* __restrict__ bias,
                           const float* __restrict__ g, const float* __restrict__ be,
                           float* __restrict__ of, bfu* __restrict__ ob,
                           const float* __restrict__ add2, int qe_mode,
                           float* __restrict__ of2, bfu* __restrict__ ob2,
                           int rows, int tile) {
  int row = tile * 4 + (threadIdx.x >> 6);
  int lane = threadIdx.x & 63;
  if (row < rows) {
    const float* pa = A + (size_t)row * 512;
    float v[8];
    float s = 0.f, s2 = 0.f;
#pragma unroll
    for (int j = 0; j < 8; ++j) {
      int c = lane + j * 64;
      float x = pa[c] + bias[c];
      for (int z = 0; z < nsplit; ++z) x += P[z * pz + (size_t)row * 512 + c];
      v[j] = x; s += x; s2 += x * x;
    }
#pragma unroll
    for (int off = 32; off > 0; off >>= 1) {
      s += __shfl_xor(s, off);
      s2 += __shfl_xor(s2, off);
    }
    float mean = s * (1.f / 512.f);
    float var = s2 * (1.f / 512.f) - mean * mean;
    float r = rsqrtf(var + 1e-5f);
    int arow = qe_mode ? (row % 100) : row;
#pragma unroll
    for (int j = 0; j < 8; ++j) {
      int c = lane + j * 64;
      float o = (v[j] - mean) * r * g[c] + be[c];
      if (of) of[(size_t)row * 512 + c] = o;
      if (ob) ob[(size_t)row * 512 + c] = f2bf(o);
      if (add2) {
        float o2 = o + add2[(size_t)arow * 512 + c];
        if (of2) of2[(size_t)row * 512 + c] = o2;
        if (ob2) ob2[(size_t)row * 512 + c] = f2bf(o2);
      }
    }
  }
}

// ---------------- standalone kernels ----------------------------------------
__global__ __launch_bounds__(256) void k_gemm_bf(const bfu* __restrict__ A,
                                                 const bfu* __restrict__ Wt,
                                                 const float* __restrict__ bias,
                                                 bfu* __restrict__ C,
                                                 int M, int N, int K, int relu,
                                                 size_t wtz, size_t cz, int bz) {
  __shared__ GemmLds L;
  int nwg = gridDim.x * gridDim.y * gridDim.z;
  int flat = blockIdx.x + gridDim.x * (blockIdx.y + gridDim.y * blockIdx.z);
  int s = xcd_swz(flat, nwg);
  int bx = s % gridDim.x; s /= gridDim.x;
  int by = s % gridDim.y;
  int bz2 = s / gridDim.y;
  dev_gemm(A, Wt + (size_t)bz2 * wtz, bias + bz2 * bz, C + (size_t)bz2 * cz,
           M, N, K, relu, by * 128, bx * 128, L);
}

__global__ __launch_bounds__(256) void k_gemm_sk(const bfu* __restrict__ A,
                                                 const bfu* __restrict__ Wt,
                                                 float* __restrict__ Pf,
                                                 int M, int N, int K, int ksplit) {
  __shared__ GemmLds L;
  int nwg = gridDim.x * gridDim.y * gridDim.z;
  int flat = blockIdx.x + gridDim.x * (blockIdx.y + gridDim.y * blockIdx.z);
  int s = xcd_swz(flat, nwg);
  int bx = s % gridDim.x; s /= gridDim.x;
  int by = s % gridDim.y;
  int z = s / gridDim.y;
  int Kc = K / ksplit;
  dev_gemm_sk(A, Wt, Pf + (size_t)z * M * N, M, N, K, z * Kc, z * Kc + Kc,
              by * 128, bx * 128, L);
}

__global__ __launch_bounds__(256) void k_attn_mfma(const bfu* __restrict__ Q, int qs,
                                                   const bfu* __restrict__ Km,
                                                   const bfu* __restrict__ Vm, int kvs,
                                                   bfu* __restrict__ O,
                                                   int Sq, int Sk) {
  __shared__ AttnLds L;
  int nwg = gridDim.x * gridDim.y * gridDim.z;
  int flat = blockIdx.x + gridDim.x * (blockIdx.y + gridDim.y * blockIdx.z);
  int s = xcd_swz(flat, nwg);
  int qblk = s % gridDim.x; s /= gridDim.x;
  int h = s % gridDim.y;
  int b = s / gridDim.y;
  dev_attn(Q, qs, Km, Vm, kvs, O, Sq, Sk, qblk, h, b, L);
}

__global__ __launch_bounds__(256) void k_ln_red(const float* __restrict__ A,
                                                const float* __restrict__ P,
                                                int nsplit, size_t pz,
                                                const float* __restrict__ bias,
                                                const float* __restrict__ g,
                                                const float* __restrict__ be,
                                                float* __restrict__ of,
                                                bfu* __restrict__ ob,
                                                const float* __restrict__ add2,
                                                int qe_mode,
                                                float* __restrict__ of2,
                                                bfu* __restrict__ ob2,
                                                int rows) {
  dev_ln_red(A, P, nsplit, pz, bias, g, be, of, ob, add2, qe_mode, of2, ob2,
             rows, blockIdx.x);
}

__global__ __launch_bounds__(256) void k_transpose2(const float* __restrict__ s0,
                                                    const float* __restrict__ s1,
                                                    float* __restrict__ d0,
                                                    float* __restrict__ d1) {
  __shared__ float tile[32][33];
  int zz = blockIdx.z;
  const float* in = (zz < 4) ? s0 : s1;
  float* out = (zz < 4) ? d0 : d1;
  int b = zz & 3;
  int c0 = blockIdx.x * 32, s0i = blockIdx.y * 32;
  int tx = threadIdx.x, ty = threadIdx.y;
  for (int i = ty; i < 32; i += 8)
    tile[i][tx] = in[((size_t)(b * 512 + c0 + i)) * 1024 + s0i + tx];
  __syncthreads();
  for (int i = ty; i < 32; i += 8)
    out[((size_t)(b * 1024 + s0i + i)) * 512 + c0 + tx] = tile[tx][i];
}

__global__ __launch_bounds__(256) void k_wt3(const float* __restrict__ s0,
                                             const float* __restrict__ s1,
                                             const float* __restrict__ s2,
                                             bfu* __restrict__ dst,
                                             int K, int N, int per) {
  __shared__ bfu tile[32][33];
  int g = blockIdx.z;
  const float* sb = (g < per) ? s0 : (g < 2 * per) ? s1 : s2;
  int gl = (g < per) ? g : (g < 2 * per) ? (g - per) : (g - 2 * per);
  const float* s = sb + (size_t)gl * (size_t)K * N;
  bfu* d = dst + (size_t)g * (size_t)K * N;
  int n0 = blockIdx.x * 32, k0 = blockIdx.y * 32;
  int tx = threadIdx.x, ty = threadIdx.y;
  for (int i = ty; i < 32; i += 8)
    tile[i][tx] = f2bf(s[(size_t)(k0 + i) * N + n0 + tx]);
  __syncthreads();
  for (int i = ty; i < 32; i += 8)
    d[(size_t)(n0 + i) * K + k0 + tx] = tile[tx][i];
}

__global__ void k_add_dual(const float* __restrict__ a, const float* __restrict__ b,
                           float* __restrict__ of, bfu* __restrict__ ob, int n4) {
  int i = blockIdx.x * blockDim.x + threadIdx.x;
  if (i >= n4) return;
  float4 x = ((const float4*)a)[i];
  float4 y = ((const float4*)b)[i];
  float4 r = make_float4(x.x + y.x, x.y + y.y, x.z + y.z, x.w + y.w);
  ((float4*)of)[i] = r;
  ((ushort4*)ob)[i] = make_ushort4(f2bf(r.x), f2bf(r.y), f2bf(r.z), f2bf(r.w));
}

__global__ void k_qe0(const float* __restrict__ qe, float* __restrict__ of,
                      bfu* __restrict__ ob) {
  int i = blockIdx.x * blockDim.x + threadIdx.x;
  if (i >= 51200) return;
  int row = i >> 7;
  int q = row % 100;
  int c4 = i & 127;
  float4 y = ((const float4*)qe)[q * 128 + c4];
  ((float4*)of)[i] = y;
  ((ushort4*)ob)[i] = make_ushort4(f2bf(y.x), f2bf(y.y), f2bf(y.z), f2bf(y.w));
}

// ---------------------------------------------------------------------------

extern "C" void kernel_launch(void* const* d_in, const int* in_sizes, int n_in,
                              void* d_out, int out_size, void* d_ws, size_t ws_size,
                              hipStream_t stream) {
  const float* src         = (const float*)d_in[0];
  const float* query_embed = (const float*)d_in[1];
  const float* pos_embed   = (const float*)d_in[2];
  const float* enc_attn_w  = (const float*)d_in[3];
  const float* enc_attn_b  = (const float*)d_in[4];
  const float* enc_w1      = (const float*)d_in[5];
  const float* enc_b1      = (const float*)d_in[6];
  const float* enc_w2      = (const float*)d_in[7];
  const float* enc_b2      = (const float*)d_in[8];
  const float* enc_ln_w    = (const float*)d_in[9];
  const float* enc_ln_b    = (const float*)d_in[10];
  const float* dec_sa_w    = (const float*)d_in[11];
  const float* dec_sa_b    = (const float*)d_in[12];
  const float* dec_ca_w    = (const float*)d_in[13];
  const float* dec_ca_b    = (const float*)d_in[14];
  const float* dec_w1      = (const float*)d_in[15];
  const float* dec_b1      = (const float*)d_in[16];
  const float* dec_w2      = (const float*)d_in[17];
  const float* dec_b2      = (const float*)d_in[18];
  const float* dec_ln_w    = (const float*)d_in[19];
  const float* dec_ln_b    = (const float*)d_in[20];
  float* out = (float*)d_out;

  const size_t ENC = 4UL * 1024 * 512;
  const size_t DEC = 4UL * 100 * 512;
  const size_t MAT = 512UL * 512;

  float* p = (float*)d_ws;
  float* x    = p; p += ENC;
  float* pos  = p; p += ENC;
  float* t1   = p; p += ENC;
  float* t2   = p; p += ENC;
  float* t3   = p; p += DEC;
  float* Pf   = p; p += 4 * ENC;   // split-K f32 partials

  bfu* bp = (bfu*)p;
  bfu* t1b    = bp; bp += ENC;
  bfu* t2b    = bp; bp += ENC;
  bfu* t3b    = bp; bp += DEC;
  bfu* qkvb   = bp; bp += 4096UL * 1536;
  bfu* aob    = bp; bp += ENC;
  bfu* hbb    = bp; bp += 4096UL * 2048;
  bfu* meminb = bp; bp += ENC;
  bfu* ckvb   = bp; bp += 6UL * 4096 * 1024;
  bfu* att_all_t = bp; bp += 72 * MAT;
  bfu* w1_all_t  = bp; bp += 12UL * 512 * 2048;
  bfu* w2_all_t  = bp; bp += 12UL * 2048 * 512;
  bfu* enc_att_t = att_all_t;
  bfu* dsa_t     = att_all_t + 24 * MAT;
  bfu* dca_t     = att_all_t + 48 * MAT;
  bfu* enc_w1t   = w1_all_t;
  bfu* dw1t      = w1_all_t + 6UL * 512 * 2048;
  bfu* enc_w2t   = w2_all_t;
  bfu* dw2t      = w2_all_t + 6UL * 2048 * 512;

  dim3 tb(32, 8);
  k_transpose2<<<dim3(16, 32, 8), tb, 0, stream>>>(src, pos_embed, x, pos);

  k_wt3<<<dim3(16, 16, 72), tb, 0, stream>>>(enc_attn_w, dec_sa_w, dec_ca_w,
                                             att_all_t, 512, 512, 24);
  k_wt3<<<dim3(64, 16, 12), tb, 0, stream>>>(enc_w1, dec_w1, dec_w1,
                                             w1_all_t, 512, 2048, 6);
  k_wt3<<<dim3(16, 64, 12), tb, 0, stream>>>(enc_w2, dec_w2, dec_w2,
                                             w2_all_t, 2048, 512, 6);

  // ----------------------------- encoder ----------------------------------
  k_add_dual<<<2048, 256, 0, stream>>>(x, pos, t1, t1b, (int)(ENC / 4));
  for (int l = 0; l < 6; ++l) {
    const bfu* awt = enc_att_t + (size_t)l * 4 * MAT;
    const float* ab = enc_attn_b + (size_t)l * 2048;
    k_gemm_bf<<<dim3(12, 32), 256, 0, stream>>>(t1b, awt, ab,
                                                qkvb, 4096, 1536, 512, 0, 0, 0, 0);
    k_attn_mfma<<<dim3(16, 8, 4), 256, 0, stream>>>(qkvb, 1536, qkvb + 512, qkvb + 1024, 1536,
                                                    aob, 1024, 1024);
    k_gemm_sk<<<dim3(4, 32, 2), 256, 0, stream>>>(aob, awt + 3 * MAT, Pf,
                                                  4096, 512, 512, 2);
    k_ln_red<<<1024, 256, 0, stream>>>(t1, Pf, 2, ENC, ab + 1536,
                                       enc_ln_w + (size_t)(l * 2 + 0) * 512,
                                       enc_ln_b + (size_t)(l * 2 + 0) * 512,
                                       t2, t2b, (const float*)nullptr, 0,
                                       (float*)nullptr, (bfu*)nullptr, 4096);
    k_gemm_bf<<<dim3(16, 32), 256, 0, stream>>>(t2b, enc_w1t + (size_t)l * 512 * 2048,
                                                enc_b1 + (size_t)l * 2048, hbb,
                                                4096, 2048, 512, 1, 0, 0, 0);
    k_gemm_sk<<<dim3(4, 32, 4), 256, 0, stream>>>(hbb, enc_w2t + (size_t)l * 2048 * 512, Pf,
                                                  4096, 512, 2048, 4);
    if (l < 5) {
      k_ln_red<<<1024, 256, 0, stream>>>(t2, Pf, 4, ENC, enc_b2 + (size_t)l * 512,
                                         enc_ln_w + (size_t)(l * 2 + 1) * 512,
                                         enc_ln_b + (size_t)(l * 2 + 1) * 512,
                                         (float*)nullptr, (bfu*)nullptr,
                                         pos, 0, t1, t1b, 4096);
    } else {
      k_ln_red<<<1024, 256, 0, stream>>>(t2, Pf, 4, ENC, enc_b2 + (size_t)l * 512,
                                         enc_ln_w + (size_t)(l * 2 + 1) * 512,
                                         enc_ln_b + (size_t)(l * 2 + 1) * 512,
                                         out + DEC, (bfu*)nullptr,
                                         pos, 0, (float*)nullptr, meminb, 4096);
    }
  }

  // all 6 decoder layers' cross-attn K/V projections in one dispatch
  k_gemm_bf<<<dim3(8, 32, 6), 256, 0, stream>>>(meminb, dca_t + MAT, dec_ca_b + 512,
                                                ckvb, 4096, 1024, 512, 0,
                                                4 * MAT, 4096UL * 1024, 2048);

  // ----------------------------- decoder ----------------------------------
  k_qe0<<<200, 256, 0, stream>>>(query_embed, t1, t1b);
  for (int l = 0; l < 6; ++l) {
    const bfu* swt = dsa_t + (size_t)l * 4 * MAT;
    const bfu* cwt = dca_t + (size_t)l * 4 * MAT;
    const float* sb = dec_sa_b + (size_t)l * 2048;
    const float* cb = dec_ca_b + (size_t)l * 2048;
    // self-attention
    k_gemm_bf<<<dim3(12, 4), 256, 0, stream>>>(t1b, swt, sb,
                                               qkvb, 400, 1536, 512, 0, 0, 0, 0);
    k_attn_mfma<<<dim3(2, 8, 4), 256, 0, stream>>>(qkvb, 1536, qkvb + 512, qkvb + 1024, 1536,
                                                   aob, 100, 100);
    k_gemm_sk<<<dim3(4, 4, 2), 256, 0, stream>>>(aob, swt + 3 * MAT, Pf,
                                                 400, 512, 512, 2);
    k_ln_red<<<100, 256, 0, stream>>>(t1, Pf, 2, 400UL * 512, sb + 1536,
                                      dec_ln_w + (size_t)(l * 3 + 0) * 512,
                                      dec_ln_b + (size_t)(l * 3 + 0) * 512,
                                      t2, t2b, (const float*)nullptr, 0,
                                      (float*)nullptr, (bfu*)nullptr, 400);
    // cross-attention
    k_gemm_bf<<<dim3(4, 4), 256, 0, stream>>>(t2b, cwt, cb,
                                              qkvb, 400, 512, 512, 0, 0, 0, 0);
    k_attn_mfma<<<dim3(2, 8, 4), 256, 0, stream>>>(qkvb, 512,
                                                   ckvb + (size_t)l * 4096 * 1024,
                                                   ckvb + (size_t)l * 4096 * 1024 + 512, 1024,
                                                   aob, 100, 1024);
    k_gemm_sk<<<dim3(4, 4, 2), 256, 0, stream>>>(aob, cwt + 3 * MAT, Pf,
                                                 400, 512, 512, 2);
    k_ln_red<<<100, 256, 0, stream>>>(t2, Pf, 2, 400UL * 512, cb + 1536,
                                      dec_ln_w + (size_t)(l * 3 + 1) * 512,
                                      dec_ln_b + (size_t)(l * 3 + 1) * 512,
                                      t3, t3b, (const float*)nullptr, 0,
                                      (float*)nullptr, (bfu*)nullptr, 400);
    // ffn
    k_gemm_bf<<<dim3(16, 4), 256, 0, stream>>>(t3b, dw1t + (size_t)l * 512 * 2048,
                                               dec_b1 + (size_t)l * 2048, hbb,
                                               400, 2048, 512, 1, 0, 0, 0);
    k_gemm_sk<<<dim3(4, 4, 4), 256, 0, stream>>>(hbb, dw2t + (size_t)l * 2048 * 512, Pf,
                                                 400, 512, 2048, 4);
    if (l < 5) {
      k_ln_red<<<100, 256, 0, stream>>>(t3, Pf, 4, 400UL * 512, dec_b2 + (size_t)l * 512,
                                        dec_ln_w + (size_t)(l * 3 + 2) * 512,
                                        dec_ln_b + (size_t)(l * 3 + 2) * 512,
                                        (float*)nullptr, (bfu*)nullptr,
                                        query_embed, 1, t1, t1b, 400);
    } else {
      k_ln_red<<<100, 256, 0, stream>>>(t3, Pf, 4, 400UL * 512, dec_b2 + (size_t)l * 512,
                                        dec_ln_w + (size_t)(l * 3 + 2) * 512,
                                        dec_ln_b + (size_t)(l * 3 + 2) * 512,
                                        out, (bfu*)nullptr, (const float*)nullptr, 0,
                                        (float*)nullptr, (bfu*)nullptr, 400);
    }
  }
}

// Round 19
// 1703.571 us; speedup vs baseline: 1.1245x; 1.0873x over previous
//
#include <hip/hip_runtime.h>
#include <math.h>

// ---------------------------------------------------------------------------
// DETR-style transformer. bf16 MFMA GEMMs (512-thread/8-wave blocks,
// global_load_lds, BK=64 2-phase dbuf, XOR-swizzled LDS, XCD block swizzle)
// + bf16 MFMA flash attention (KVBLK=128, setprio). Split-K GEMMs -> f32
// partials; k_ln_red fuses reduce+bias+residual+LN+re-add.
// B=4, S=1024, NQ=100, D=512, H=8, dk=64, FF=2048, L=6
// ---------------------------------------------------------------------------

typedef unsigned short bfu;
typedef unsigned int u32;
typedef __bf16 bf8v __attribute__((ext_vector_type(8)));
typedef float f32x4 __attribute__((ext_vector_type(4)));

__device__ inline bfu f2bf(float f) {
  union { float f; u32 u; } v; v.f = f;
  u32 u = v.u;
  u32 r = (u + 0x7fffu + ((u >> 16) & 1u)) >> 16;
  return (bfu)r;
}
__device__ inline float bflo(u32 u) { return __uint_as_float(u << 16); }

typedef const __attribute__((address_space(1))) u32 gas_t;
typedef __attribute__((address_space(3))) u32 las_t;
__device__ __forceinline__ void gl16(const void* g, void* l) {
  __builtin_amdgcn_global_load_lds((gas_t*)g, (las_t*)l, 16, 0, 0);
}

// bijective XCD swizzle (m204): consecutive logical tiles -> same XCD chunk
__device__ __forceinline__ int xcd_swz(int flat, int nwg) {
  int q = nwg >> 3, r = nwg & 7;
  int xcd = flat & 7, idx = flat >> 3;
  return (xcd < r ? xcd * (q + 1) : r * (q + 1) + (xcd - r) * q) + idx;
}

struct GemmLds { bfu As[2][128][64]; bfu Bs[2][128][64]; };      // 64 KB
struct AttnLds { bfu Ks[128][72]; bfu Vt[64][136]; bfu Sm[4][16][136]; };  // 52 KB

// ---------------- device GEMM body: 8 waves, BK=64, gl_lds, 2-phase dbuf ---
// Wave w (0..7): wm=w>>1 (0..3) -> 32 C-rows; wn=w&1 (0..1) -> 64 C-cols.
__device__ void dev_gemm(const bfu* __restrict__ A, const bfu* __restrict__ Wt,
                         const float* __restrict__ bias, bfu* __restrict__ C,
                         int M, int N, int K, int relu, int bm, int bn,
                         GemmLds& L) {
  int t = threadIdx.x;
  int wave = t >> 6, lane = t & 63;
  int wm = wave >> 1, wn = wave & 1;
  int l15 = lane & 15, l4 = lane >> 4;
  f32x4 acc[2][4];
  f32x4 zz = {0.f, 0.f, 0.f, 0.f};
#pragma unroll
  for (int mi = 0; mi < 2; ++mi)
#pragma unroll
    for (int ni = 0; ni < 4; ++ni) acc[mi][ni] = zz;

  auto stage = [&](int buf, int k0) {
#pragma unroll
    for (int i = 0; i < 2; ++i) {
      int c = t + i * 512;            // 0..1023 chunks of 16B
      int row = c >> 3, kg = c & 7;
      int sc = kg ^ (row & 7);
      if (bm + row < M)
        gl16(A + (size_t)(bm + row) * K + k0 + sc * 8, &L.As[buf][row][kg * 8]);
      gl16(Wt + (size_t)(bn + row) * K + k0 + sc * 8, &L.Bs[buf][row][kg * 8]);
    }
  };
  stage(0, 0);
  int cur = 0;
  for (int k0 = 0; k0 < K; k0 += 64) {
    __syncthreads();
    if (k0 + 64 < K) stage(cur ^ 1, k0 + 64);
#pragma unroll
    for (int kc = 0; kc < 2; ++kc) {
      bf8v av[2], bv[4];
#pragma unroll
      for (int mi = 0; mi < 2; ++mi) {
        int row = wm * 32 + mi * 16 + l15;
        av[mi] = *(const bf8v*)&L.As[cur][row][((kc * 4 + l4) ^ (row & 7)) * 8];
      }
#pragma unroll
      for (int ni = 0; ni < 4; ++ni) {
        int row = wn * 64 + ni * 16 + l15;
        bv[ni] = *(const bf8v*)&L.Bs[cur][row][((kc * 4 + l4) ^ (row & 7)) * 8];
      }
#pragma unroll
      for (int mi = 0; mi < 2; ++mi)
#pragma unroll
        for (int ni = 0; ni < 4; ++ni)
          acc[mi][ni] = __builtin_amdgcn_mfma_f32_16x16x32_bf16(av[mi], bv[ni],
                                                                acc[mi][ni], 0, 0, 0);
    }
    cur ^= 1;
  }

#pragma unroll
  for (int mi = 0; mi < 2; ++mi) {
    int row0 = bm + wm * 32 + mi * 16 + l4 * 4;
#pragma unroll
    for (int ni = 0; ni < 4; ++ni) {
      int col = bn + wn * 64 + ni * 16 + l15;
      float bb = bias[col];
#pragma unroll
      for (int r = 0; r < 4; ++r) {
        int row = row0 + r;
        if (row < M) {
          float v = acc[mi][ni][r] + bb;
          if (relu) v = fmaxf(v, 0.f);
          C[(size_t)row * N + col] = f2bf(v);
        }
      }
    }
  }
}

// ---------------- device split-K GEMM -> f32 partials (8 waves) ------------
__device__ void dev_gemm_sk(const bfu* __restrict__ A, const bfu* __restrict__ Wt,
                            float* __restrict__ Pf, int M, int N, int K,
                            int kbeg, int kend, int bm, int bn, GemmLds& L) {
  int t = threadIdx.x;
  int wave = t >> 6, lane = t & 63;
  int wm = wave >> 1, wn = wave & 1;
  int l15 = lane & 15, l4 = lane >> 4;
  f32x4 acc[2][4];
  f32x4 zz = {0.f, 0.f, 0.f, 0.f};
#pragma unroll
  for (int mi = 0; mi < 2; ++mi)
#pragma unroll
    for (int ni = 0; ni < 4; ++ni) acc[mi][ni] = zz;

  auto stage = [&](int buf, int k0) {
#pragma unroll
    for (int i = 0; i < 2; ++i) {
      int c = t + i * 512;
      int row = c >> 3, kg = c & 7;
      int sc = kg ^ (row & 7);
      if (bm + row < M)
        gl16(A + (size_t)(bm + row) * K + k0 + sc * 8, &L.As[buf][row][kg * 8]);
      gl16(Wt + (size_t)(bn + row) * K + k0 + sc * 8, &L.Bs[buf][row][kg * 8]);
    }
  };
  stage(0, kbeg);
  int cur = 0;
  for (int k0 = kbeg; k0 < kend; k0 += 64) {
    __syncthreads();
    if (k0 + 64 < kend) stage(cur ^ 1, k0 + 64);
#pragma unroll
    for (int kc = 0; kc < 2; ++kc) {
      bf8v av[2], bv[4];
#pragma unroll
      for (int mi = 0; mi < 2; ++mi) {
        int row = wm * 32 + mi * 16 + l15;
        av[mi] = *(const bf8v*)&L.As[cur][row][((kc * 4 + l4) ^ (row & 7)) * 8];
      }
#pragma unroll
      for (int ni = 0; ni < 4; ++ni) {
        int row = wn * 64 + ni * 16 + l15;
        bv[ni] = *(const bf8v*)&L.Bs[cur][row][((kc * 4 + l4) ^ (row & 7)) * 8];
      }
#pragma unroll
      for (int mi = 0; mi < 2; ++mi)
#pragma unroll
        for (int ni = 0; ni < 4; ++ni)
          acc[mi][ni] = __builtin_amdgcn_mfma_f32_16x16x32_bf16(av[mi], bv[ni],
                                                                acc[mi][ni], 0, 0, 0);
    }
    cur ^= 1;
  }

#pragma unroll
  for (int mi = 0; mi < 2; ++mi) {
    int row0 = bm + wm * 32 + mi * 16 + l4 * 4;
#pragma unroll
    for (int ni = 0; ni < 4; ++ni) {
      int col = bn + wn * 64 + ni * 16 + l15;
#pragma unroll
      for (int r = 0; r < 4; ++r) {
        int row = row0 + r;
        if (row < M) Pf[(size_t)row * N + col] = acc[mi][ni][r];
      }
    }
  }
}

// ---------------- device flash attention, KVBLK=128 ------------------------
__device__ void dev_attn(const bfu* __restrict__ Q, int qs,
                         const bfu* __restrict__ Km,
                         const bfu* __restrict__ Vm, int kvs,
                         bfu* __restrict__ O, int Sq, int Sk,
                         int qblk, int h, int b, AttnLds& L) {
  const float scale = 0.125f;
  int q0 = qblk * 64;
  int t = threadIdx.x;
  int wave = t >> 6, lane = t & 63;
  int l15 = lane & 15, l4 = lane >> 4;
  int hoff = h * 64;

  uint4 uq0 = {0u, 0u, 0u, 0u}, uq1 = {0u, 0u, 0u, 0u};
  {
    int qrow = q0 + wave * 16 + l15;
    if (qrow < Sq) {
      const bfu* qp = Q + (size_t)(b * Sq + qrow) * qs + hoff + l4 * 8;
      uq0 = *(const uint4*)qp;
      uq1 = *(const uint4*)(qp + 32);
    }
  }
  bf8v qf0 = *(bf8v*)&uq0, qf1 = *(bf8v*)&uq1;

  float m_[4] = {-1e30f, -1e30f, -1e30f, -1e30f};
  float l_[4] = {0.f, 0.f, 0.f, 0.f};
  f32x4 oacc[4];
  f32x4 zz = {0.f, 0.f, 0.f, 0.f};
#pragma unroll
  for (int n = 0; n < 4; ++n) oacc[n] = zz;

  uint4 ruk[4], ruv[4];
  const uint4 uz = {0u, 0u, 0u, 0u};
  auto load_kv = [&](int k0) {
#pragma unroll
    for (int i = 0; i < 4; ++i) {
      int e = t + i * 256;
      int rk = e >> 3, cg = e & 7;
      ruk[i] = uz;
      if (k0 + rk < Sk)
        ruk[i] = *(const uint4*)(Km + (size_t)(b * Sk + k0 + rk) * kvs + hoff + cg * 8);
      int kv = e & 127, dg = e >> 7;
      ruv[i] = uz;
      if (k0 + kv < Sk)
        ruv[i] = *(const uint4*)(Vm + (size_t)(b * Sk + k0 + kv) * kvs + hoff + dg * 8);
    }
  };
  load_kv(0);

  for (int k0 = 0; k0 < Sk; k0 += 128) {
#pragma unroll
    for (int i = 0; i < 4; ++i) {
      int e = t + i * 256;
      int rk = e >> 3, cg = e & 7;
      *(uint4*)&L.Ks[rk][cg * 8] = ruk[i];
      int kv = e & 127, dg = e >> 7;
      bfu vv[8];
      *(uint4*)vv = ruv[i];
#pragma unroll
      for (int j = 0; j < 8; ++j) L.Vt[dg * 8 + j][kv] = vv[j];
    }
    __syncthreads();
    if (k0 + 128 < Sk) load_kv(k0 + 128);

    f32x4 s4[8];
    __builtin_amdgcn_s_setprio(1);
#pragma unroll
    for (int tt = 0; tt < 8; ++tt) {
      bf8v kf0 = *(const bf8v*)&L.Ks[tt * 16 + l15][l4 * 8];
      bf8v kf1 = *(const bf8v*)&L.Ks[tt * 16 + l15][32 + l4 * 8];
      f32x4 a = zz;
      a = __builtin_amdgcn_mfma_f32_16x16x32_bf16(qf0, kf0, a, 0, 0, 0);
      a = __builtin_amdgcn_mfma_f32_16x16x32_bf16(qf1, kf1, a, 0, 0, 0);
      s4[tt] = a;
    }
    __builtin_amdgcn_s_setprio(0);

    bool full = (k0 + 128 <= Sk);
    float f_[4];
#pragma unroll
    for (int r = 0; r < 4; ++r) {
      float sv[8];
      float mx = -1e30f;
      if (full) {
#pragma unroll
        for (int tt = 0; tt < 8; ++tt) {
          float s = s4[tt][r] * scale;
          sv[tt] = s;
          mx = fmaxf(mx, s);
        }
      } else {
#pragma unroll
        for (int tt = 0; tt < 8; ++tt) {
          float s = s4[tt][r] * scale;
          s = (k0 + tt * 16 + l15 < Sk) ? s : -1e30f;
          sv[tt] = s;
          mx = fmaxf(mx, s);
        }
      }
#pragma unroll
      for (int off = 1; off < 16; off <<= 1) mx = fmaxf(mx, __shfl_xor(mx, off));
      float nm = fmaxf(m_[r], mx);
      float f = __expf(m_[r] - nm);
      float ps = 0.f;
#pragma unroll
      for (int tt = 0; tt < 8; ++tt) {
        float p = __expf(sv[tt] - nm);
        ps += p;
        L.Sm[wave][l4 * 4 + r][tt * 16 + l15] = f2bf(p);
      }
#pragma unroll
      for (int off = 1; off < 16; off <<= 1) ps += __shfl_xor(ps, off);
      l_[r] = l_[r] * f + ps;
      m_[r] = nm;
      f_[r] = f;
    }
#pragma unroll
    for (int n = 0; n < 4; ++n)
#pragma unroll
      for (int r = 0; r < 4; ++r) oacc[n][r] *= f_[r];

    __builtin_amdgcn_s_setprio(1);
#pragma unroll
    for (int h2 = 0; h2 < 2; ++h2) {
      bf8v p0 = *(const bf8v*)&L.Sm[wave][l15][h2 * 64 + l4 * 8];
      bf8v p1 = *(const bf8v*)&L.Sm[wave][l15][h2 * 64 + 32 + l4 * 8];
#pragma unroll
      for (int n = 0; n < 4; ++n) {
        bf8v v0 = *(const bf8v*)&L.Vt[n * 16 + l15][h2 * 64 + l4 * 8];
        bf8v v1 = *(const bf8v*)&L.Vt[n * 16 + l15][h2 * 64 + 32 + l4 * 8];
        oacc[n] = __builtin_amdgcn_mfma_f32_16x16x32_bf16(p0, v0, oacc[n], 0, 0, 0);
        oacc[n] = __builtin_amdgcn_mfma_f32_16x16x32_bf16(p1, v1, oacc[n], 0, 0, 0);
      }
    }
    __builtin_amdgcn_s_setprio(0);
    __syncthreads();
  }

#pragma unroll
  for (int r = 0; r < 4; ++r) {
    int row = q0 + wave * 16 + l4 * 4 + r;
    if (row < Sq) {
      float inv = 1.f / l_[r];
#pragma unroll
      for (int n = 0; n < 4; ++n)
        O[(size_t)(b * Sq + row) * 512 + hoff + n * 16 + l15] = f2bf(oacc[n][r] * inv);
    }
  }
}

// ---------------- device LN(A + sum_z P[z] + bias), fused epilogues --------
__device__ void dev_ln_red(const float* __restrict__ A, const float* __restrict__ P,
                           int nsplit, size_t pz, const float* __restrict__ bias,
                           const float* __restrict__ g, const float* __restrict__ be,
                           float* __restrict__ of, bfu* __restrict__ ob,
                           const float* __restrict__ add2, int qe_mode,
                           float* __restrict__ of2, bfu* __restrict__ ob2,
                           int rows, int tile) {
  int row = tile * 4 + (threadIdx.x >> 6);
  int lane = threadIdx.x & 63;
  if (row < rows) {
    const float* pa = A + (size_t)row * 512;
    float v[8];
    float s = 0.f, s2 = 0.f;
#pragma unroll
    for (int j = 0; j < 8; ++j) {
      int c = lane + j * 64;
      float x = pa[c] + bias[c];
      for (int z = 0; z < nsplit; ++z) x += P[z * pz + (size_t)row * 512 + c];
      v[j] = x; s += x; s2 += x * x;
    }
#pragma unroll
    for (int off = 32; off > 0; off >>= 1) {
      s += __shfl_xor(s, off);
      s2 += __shfl_xor(s2, off);
    }
    float mean = s * (1.f / 512.f);
    float var = s2 * (1.f / 512.f) - mean * mean;
    float r = rsqrtf(var + 1e-5f);
    int arow = qe_mode ? (row % 100) : row;
#pragma unroll
    for (int j = 0; j < 8; ++j) {
      int c = lane + j * 64;
      float o = (v[j] - mean) * r * g[c] + be[c];
      if (of) of[(size_t)row * 512 + c] = o;
      if (ob) ob[(size_t)row * 512 + c] = f2bf(o);
      if (add2) {
        float o2 = o + add2[(size_t)arow * 512 + c];
        if (of2) of2[(size_t)row * 512 + c] = o2;
        if (ob2) ob2[(size_t)row * 512 + c] = f2bf(o2);
      }
    }
  }
}

// ---------------- standalone kernels ----------------------------------------
__global__ __launch_bounds__(512) void k_gemm_bf(const bfu* __restrict__ A,
                                                 const bfu* __restrict__ Wt,
                                                 const float* __restrict__ bias,
                                                 bfu* __restrict__ C,
                                                 int M, int N, int K, int relu,
                                                 size_t wtz, size_t cz, int bz) {
  __shared__ GemmLds L;
  int nwg = gridDim.x * gridDim.y * gridDim.z;
  int flat = blockIdx.x + gridDim.x * (blockIdx.y + gridDim.y * blockIdx.z);
  int s = xcd_swz(flat, nwg);
  int bx = s % gridDim.x; s /= gridDim.x;
  int by = s % gridDim.y;
  int bz2 = s / gridDim.y;
  dev_gemm(A, Wt + (size_t)bz2 * wtz, bias + bz2 * bz, C + (size_t)bz2 * cz,
           M, N, K, relu, by * 128, bx * 128, L);
}

__global__ __launch_bounds__(512) void k_gemm_sk(const bfu* __restrict__ A,
                                                 const bfu* __restrict__ Wt,
                                                 float* __restrict__ Pf,
                                                 int M, int N, int K, int ksplit) {
  __shared__ GemmLds L;
  int nwg = gridDim.x * gridDim.y * gridDim.z;
  int flat = blockIdx.x + gridDim.x * (blockIdx.y + gridDim.y * blockIdx.z);
  int s = xcd_swz(flat, nwg);
  int bx = s % gridDim.x; s /= gridDim.x;
  int by = s % gridDim.y;
  int z = s / gridDim.y;
  int Kc = K / ksplit;
  dev_gemm_sk(A, Wt, Pf + (size_t)z * M * N, M, N, K, z * Kc, z * Kc + Kc,
              by * 128, bx * 128, L);
}

__global__ __launch_bounds__(256) void k_attn_mfma(const bfu* __restrict__ Q, int qs,
                                                   const bfu* __restrict__ Km,
                                                   const bfu* __restrict__ Vm, int kvs,
                                                   bfu* __restrict__ O,
                                                   int Sq, int Sk) {
  __shared__ AttnLds L;
  int nwg = gridDim.x * gridDim.y * gridDim.z;
  int flat = blockIdx.x + gridDim.x * (blockIdx.y + gridDim.y * blockIdx.z);
  int s = xcd_swz(flat, nwg);
  int qblk = s % gridDim.x; s /= gridDim.x;
  int h = s % gridDim.y;
  int b = s / gridDim.y;
  dev_attn(Q, qs, Km, Vm, kvs, O, Sq, Sk, qblk, h, b, L);
}

__global__ __launch_bounds__(256) void k_ln_red(const float* __restrict__ A,
                                                const float* __restrict__ P,
                                                int nsplit, size_t pz,
                                                const float* __restrict__ bias,
                                                const float* __restrict__ g,
                                                const float* __restrict__ be,
                                                float* __restrict__ of,
                                                bfu* __restrict__ ob,
                                                const float* __restrict__ add2,
                                                int qe_mode,
                                                float* __restrict__ of2,
                                                bfu* __restrict__ ob2,
                                                int rows) {
  dev_ln_red(A, P, nsplit, pz, bias, g, be, of, ob, add2, qe_mode, of2, ob2,
             rows, blockIdx.x);
}

__global__ __launch_bounds__(256) void k_transpose2(const float* __restrict__ s0,
                                                    const float* __restrict__ s1,
                                                    float* __restrict__ d0,
                                                    float* __restrict__ d1) {
  __shared__ float tile[32][33];
  int zz = blockIdx.z;
  const float* in = (zz < 4) ? s0 : s1;
  float* out = (zz < 4) ? d0 : d1;
  int b = zz & 3;
  int c0 = blockIdx.x * 32, s0i = blockIdx.y * 32;
  int tx = threadIdx.x, ty = threadIdx.y;
  for (int i = ty; i < 32; i += 8)
    tile[i][tx] = in[((size_t)(b * 512 + c0 + i)) * 1024 + s0i + tx];
  __syncthreads();
  for (int i = ty; i < 32; i += 8)
    out[((size_t)(b * 1024 + s0i + i)) * 512 + c0 + tx] = tile[tx][i];
}

__global__ __launch_bounds__(256) void k_wt3(const float* __restrict__ s0,
                                             const float* __restrict__ s1,
                                             const float* __restrict__ s2,
                                             bfu* __restrict__ dst,
                                             int K, int N, int per) {
  __shared__ bfu tile[32][33];
  int g = blockIdx.z;
  const float* sb = (g < per) ? s0 : (g < 2 * per) ? s1 : s2;
  int gl = (g < per) ? g : (g < 2 * per) ? (g - per) : (g - 2 * per);
  const float* s = sb + (size_t)gl * (size_t)K * N;
  bfu* d = dst + (size_t)g * (size_t)K * N;
  int n0 = blockIdx.x * 32, k0 = blockIdx.y * 32;
  int tx = threadIdx.x, ty = threadIdx.y;
  for (int i = ty; i < 32; i += 8)
    tile[i][tx] = f2bf(s[(size_t)(k0 + i) * N + n0 + tx]);
  __syncthreads();
  for (int i = ty; i < 32; i += 8)
    d[(size_t)(n0 + i) * K + k0 + tx] = tile[tx][i];
}

__global__ void k_add_dual(const float* __restrict__ a, const float* __restrict__ b,
                           float* __restrict__ of, bfu* __restrict__ ob, int n4) {
  int i = blockIdx.x * blockDim.x + threadIdx.x;
  if (i >= n4) return;
  float4 x = ((const float4*)a)[i];
  float4 y = ((const float4*)b)[i];
  float4 r = make_float4(x.x + y.x, x.y + y.y, x.z + y.z, x.w + y.w);
  ((float4*)of)[i] = r;
  ((ushort4*)ob)[i] = make_ushort4(f2bf(r.x), f2bf(r.y), f2bf(r.z), f2bf(r.w));
}

__global__ void k_qe0(const float* __restrict__ qe, float* __restrict__ of,
                      bfu* __restrict__ ob) {
  int i = blockIdx.x * blockDim.x + threadIdx.x;
  if (i >= 51200) return;
  int row = i >> 7;
  int q = row % 100;
  int c4 = i & 127;
  float4 y = ((const float4*)qe)[q * 128 + c4];
  ((float4*)of)[i] = y;
  ((ushort4*)ob)[i] = make_ushort4(f2bf(y.x), f2bf(y.y), f2bf(y.z), f2bf(y.w));
}

// ---------------------------------------------------------------------------

extern "C" void kernel_launch(void* const* d_in, const int* in_sizes, int n_in,
                              void* d_out, int out_size, void* d_ws, size_t ws_size,
                              hipStream_t stream) {
  const float* src         = (const float*)d_in[0];
  const float* query_embed = (const float*)d_in[1];
  const float* pos_embed   = (const float*)d_in[2];
  const float* enc_attn_w  = (const float*)d_in[3];
  const float* enc_attn_b  = (const float*)d_in[4];
  const float* enc_w1      = (const float*)d_in[5];
  const float* enc_b1      = (const float*)d_in[6];
  const float* enc_w2      = (const float*)d_in[7];
  const float* enc_b2      = (const float*)d_in[8];
  const float* enc_ln_w    = (const float*)d_in[9];
  const float* enc_ln_b    = (const float*)d_in[10];
  const float* dec_sa_w    = (const float*)d_in[11];
  const float* dec_sa_b    = (const float*)d_in[12];
  const float* dec_ca_w    = (const float*)d_in[13];
  const float* dec_ca_b    = (const float*)d_in[14];
  const float* dec_w1      = (const float*)d_in[15];
  const float* dec_b1      = (const float*)d_in[16];
  const float* dec_w2      = (const float*)d_in[17];
  const float* dec_b2      = (const float*)d_in[18];
  const float* dec_ln_w    = (const float*)d_in[19];
  const float* dec_ln_b    = (const float*)d_in[20];
  float* out = (float*)d_out;

  const size_t ENC = 4UL * 1024 * 512;
  const size_t DEC = 4UL * 100 * 512;
  const size_t MAT = 512UL * 512;

  float* p = (float*)d_ws;
  float* x    = p; p += ENC;
  float* pos  = p; p += ENC;
  float* t1   = p; p += ENC;
  float* t2   = p; p += ENC;
  float* t3   = p; p += DEC;
  float* Pf   = p; p += 4 * ENC;   // split-K f32 partials

  bfu* bp = (bfu*)p;
  bfu* t1b    = bp; bp += ENC;
  bfu* t2b    = bp; bp += ENC;
  bfu* t3b    = bp; bp += DEC;
  bfu* qkvb   = bp; bp += 4096UL * 1536;
  bfu* aob    = bp; bp += ENC;
  bfu* hbb    = bp; bp += 4096UL * 2048;
  bfu* meminb = bp; bp += ENC;
  bfu* ckvb   = bp; bp += 6UL * 4096 * 1024;
  bfu* att_all_t = bp; bp += 72 * MAT;
  bfu* w1_all_t  = bp; bp += 12UL * 512 * 2048;
  bfu* w2_all_t  = bp; bp += 12UL * 2048 * 512;
  bfu* enc_att_t = att_all_t;
  bfu* dsa_t     = att_all_t + 24 * MAT;
  bfu* dca_t     = att_all_t + 48 * MAT;
  bfu* enc_w1t   = w1_all_t;
  bfu* dw1t      = w1_all_t + 6UL * 512 * 2048;
  bfu* enc_w2t   = w2_all_t;
  bfu* dw2t      = w2_all_t + 6UL * 2048 * 512;

  dim3 tb(32, 8);
  k_transpose2<<<dim3(16, 32, 8), tb, 0, stream>>>(src, pos_embed, x, pos);

  k_wt3<<<dim3(16, 16, 72), tb, 0, stream>>>(enc_attn_w, dec_sa_w, dec_ca_w,
                                             att_all_t, 512, 512, 24);
  k_wt3<<<dim3(64, 16, 12), tb, 0, stream>>>(enc_w1, dec_w1, dec_w1,
                                             w1_all_t, 512, 2048, 6);
  k_wt3<<<dim3(16, 64, 12), tb, 0, stream>>>(enc_w2, dec_w2, dec_w2,
                                             w2_all_t, 2048, 512, 6);

  // ----------------------------- encoder ----------------------------------
  k_add_dual<<<2048, 256, 0, stream>>>(x, pos, t1, t1b, (int)(ENC / 4));
  for (int l = 0; l < 6; ++l) {
    const bfu* awt = enc_att_t + (size_t)l * 4 * MAT;
    const float* ab = enc_attn_b + (size_t)l * 2048;
    k_gemm_bf<<<dim3(12, 32), 512, 0, stream>>>(t1b, awt, ab,
                                                qkvb, 4096, 1536, 512, 0, 0, 0, 0);
    k_attn_mfma<<<dim3(16, 8, 4), 256, 0, stream>>>(qkvb, 1536, qkvb + 512, qkvb + 1024, 1536,
                                                    aob, 1024, 1024);
    k_gemm_sk<<<dim3(4, 32, 2), 512, 0, stream>>>(aob, awt + 3 * MAT, Pf,
                                                  4096, 512, 512, 2);
    k_ln_red<<<1024, 256, 0, stream>>>(t1, Pf, 2, ENC, ab + 1536,
                                       enc_ln_w + (size_t)(l * 2 + 0) * 512,
                                       enc_ln_b + (size_t)(l * 2 + 0) * 512,
                                       t2, t2b, (const float*)nullptr, 0,
                                       (float*)nullptr, (bfu*)nullptr, 4096);
    k_gemm_bf<<<dim3(16, 32), 512, 0, stream>>>(t2b, enc_w1t + (size_t)l * 512 * 2048,
                                                enc_b1 + (size_t)l * 2048, hbb,
                                                4096, 2048, 512, 1, 0, 0, 0);
    k_gemm_sk<<<dim3(4, 32, 4), 512, 0, stream>>>(hbb, enc_w2t + (size_t)l * 2048 * 512, Pf,
                                                  4096, 512, 2048, 4);
    if (l < 5) {
      k_ln_red<<<1024, 256, 0, stream>>>(t2, Pf, 4, ENC, enc_b2 + (size_t)l * 512,
                                         enc_ln_w + (size_t)(l * 2 + 1) * 512,
                                         enc_ln_b + (size_t)(l * 2 + 1) * 512,
                                         (float*)nullptr, (bfu*)nullptr,
                                         pos, 0, t1, t1b, 4096);
    } else {
      k_ln_red<<<1024, 256, 0, stream>>>(t2, Pf, 4, ENC, enc_b2 + (size_t)l * 512,
                                         enc_ln_w + (size_t)(l * 2 + 1) * 512,
                                         enc_ln_b + (size_t)(l * 2 + 1) * 512,
                                         out + DEC, (bfu*)nullptr,
                                         pos, 0, (float*)nullptr, meminb, 4096);
    }
  }

  // all 6 decoder layers' cross-attn K/V projections in one dispatch
  k_gemm_bf<<<dim3(8, 32, 6), 512, 0, stream>>>(meminb, dca_t + MAT, dec_ca_b + 512,
                                                ckvb, 4096, 1024, 512, 0,
                                                4 * MAT, 4096UL * 1024, 2048);

  // ----------------------------- decoder ----------------------------------
  k_qe0<<<200, 256, 0, stream>>>(query_embed, t1, t1b);
  for (int l = 0; l < 6; ++l) {
    const bfu* swt = dsa_t + (size_t)l * 4 * MAT;
    const bfu* cwt = dca_t + (size_t)l * 4 * MAT;
    const float* sb = dec_sa_b + (size_t)l * 2048;
    const float* cb = dec_ca_b + (size_t)l * 2048;
    // self-attention
    k_gemm_bf<<<dim3(12, 4), 512, 0, stream>>>(t1b, swt, sb,
                                               qkvb, 400, 1536, 512, 0, 0, 0, 0);
    k_attn_mfma<<<dim3(2, 8, 4), 256, 0, stream>>>(qkvb, 1536, qkvb + 512, qkvb + 1024, 1536,
                                                   aob, 100, 100);
    k_gemm_sk<<<dim3(4, 4, 2), 512, 0, stream>>>(aob, swt + 3 * MAT, Pf,
                                                 400, 512, 512, 2);
    k_ln_red<<<100, 256, 0, stream>>>(t1, Pf, 2, 400UL * 512, sb + 1536,
                                      dec_ln_w + (size_t)(l * 3 + 0) * 512,
                                      dec_ln_b + (size_t)(l * 3 + 0) * 512,
                                      t2, t2b, (const float*)nullptr, 0,
                                      (float*)nullptr, (bfu*)nullptr, 400);
    // cross-attention
    k_gemm_bf<<<dim3(4, 4), 512, 0, stream>>>(t2b, cwt, cb,
                                              qkvb, 400, 512, 512, 0, 0, 0, 0);
    k_attn_mfma<<<dim3(2, 8, 4), 256, 0, stream>>>(qkvb, 512,
                                                   ckvb + (size_t)l * 4096 * 1024,
                                                   ckvb + (size_t)l * 4096 * 1024 + 512, 1024,
                                                   aob, 100, 1024);
    k_gemm_sk<<<dim3(4, 4, 2), 512, 0, stream>>>(aob, cwt + 3 * MAT, Pf,
                                                 400, 512, 512, 2);
    k_ln_red<<<100, 256, 0, stream>>>(t2, Pf, 2, 400UL * 512, cb + 1536,
                                      dec_ln_w + (size_t)(l * 3 + 1) * 512,
                                      dec_ln_b + (size_t)(l * 3 + 1) * 512,
                                      t3, t3b, (const float*)nullptr, 0,
                                      (float*)nullptr, (bfu*)nullptr, 400);
    // ffn
    k_gemm_bf<<<dim3(16, 4), 512, 0, stream>>>(t3b, dw1t + (size_t)l * 512 * 2048,
                                               dec_b1 + (size_t)l * 2048, hbb,
                                               400, 2048, 512, 1, 0, 0, 0);
    k_gemm_sk<<<dim3(4, 4, 4), 512, 0, stream>>>(hbb, dw2t + (size_t)l * 2048 * 512, Pf,
                                                 400, 512, 2048, 4);
    if (l < 5) {
      k_ln_red<<<100, 256, 0, stream>>>(t3, Pf, 4, 400UL * 512, dec_b2 + (size_t)l * 512,
                                        dec_ln_w + (size_t)(l * 3 + 2) * 512,
                                        dec_ln_b + (size_t)(l * 3 + 2) * 512,
                                        (float*)nullptr, (bfu*)nullptr,
                                        query_embed, 1, t1, t1b, 400);
    } else {
      k_ln_red<<<100, 256, 0, stream>>>(t3, Pf, 4, 400UL * 512, dec_b2 + (size_t)l * 512,
                                        dec_ln_w + (size_t)(l * 3 + 2) * 512,
                                        dec_ln_b + (size_t)(l * 3 + 2) * 512,
                                        out, (bfu*)nullptr, (const float*)nullptr, 0,
                                        (float*)nullptr, (bfu*)nullptr, 400);
    }
  }
}

// Round 20
// 1697.902 us; speedup vs baseline: 1.1282x; 1.0033x over previous
//
#include <hip/hip_runtime.h>
#include <math.h>

// ---------------------------------------------------------------------------
// DETR-style transformer. bf16 MFMA GEMMs (512-thread/8-wave blocks,
// global_load_lds, BK=64 2-phase dbuf, XOR-swizzled LDS, XCD block swizzle)
// + bf16 MFMA flash attention (512-thread/8-wave, 128 q-rows, KVBLK=128,
// setprio). Split-K GEMMs -> f32 partials; k_ln_red fuses
// reduce+bias+residual+LN+re-add.
// B=4, S=1024, NQ=100, D=512, H=8, dk=64, FF=2048, L=6
// ---------------------------------------------------------------------------

typedef unsigned short bfu;
typedef unsigned int u32;
typedef __bf16 bf8v __attribute__((ext_vector_type(8)));
typedef float f32x4 __attribute__((ext_vector_type(4)));

__device__ inline bfu f2bf(float f) {
  union { float f; u32 u; } v; v.f = f;
  u32 u = v.u;
  u32 r = (u + 0x7fffu + ((u >> 16) & 1u)) >> 16;
  return (bfu)r;
}
__device__ inline float bflo(u32 u) { return __uint_as_float(u << 16); }

typedef const __attribute__((address_space(1))) u32 gas_t;
typedef __attribute__((address_space(3))) u32 las_t;
__device__ __forceinline__ void gl16(const void* g, void* l) {
  __builtin_amdgcn_global_load_lds((gas_t*)g, (las_t*)l, 16, 0, 0);
}

// bijective XCD swizzle (m204): consecutive logical tiles -> same XCD chunk
__device__ __forceinline__ int xcd_swz(int flat, int nwg) {
  int q = nwg >> 3, r = nwg & 7;
  int xcd = flat & 7, idx = flat >> 3;
  return (xcd < r ? xcd * (q + 1) : r * (q + 1) + (xcd - r) * q) + idx;
}

struct GemmLds { bfu As[2][128][64]; bfu Bs[2][128][64]; };      // 64 KB
struct AttnLds { bfu Ks[128][72]; bfu Vt[64][136]; bfu Sm[8][16][136]; };  // ~70 KB

// ---------------- device GEMM body: 8 waves, BK=64, gl_lds, 2-phase dbuf ---
__device__ void dev_gemm(const bfu* __restrict__ A, const bfu* __restrict__ Wt,
                         const float* __restrict__ bias, bfu* __restrict__ C,
                         int M, int N, int K, int relu, int bm, int bn,
                         GemmLds& L) {
  int t = threadIdx.x;
  int wave = t >> 6, lane = t & 63;
  int wm = wave >> 1, wn = wave & 1;
  int l15 = lane & 15, l4 = lane >> 4;
  f32x4 acc[2][4];
  f32x4 zz = {0.f, 0.f, 0.f, 0.f};
#pragma unroll
  for (int mi = 0; mi < 2; ++mi)
#pragma unroll
    for (int ni = 0; ni < 4; ++ni) acc[mi][ni] = zz;

  auto stage = [&](int buf, int k0) {
#pragma unroll
    for (int i = 0; i < 2; ++i) {
      int c = t + i * 512;
      int row = c >> 3, kg = c & 7;
      int sc = kg ^ (row & 7);
      if (bm + row < M)
        gl16(A + (size_t)(bm + row) * K + k0 + sc * 8, &L.As[buf][row][kg * 8]);
      gl16(Wt + (size_t)(bn + row) * K + k0 + sc * 8, &L.Bs[buf][row][kg * 8]);
    }
  };
  stage(0, 0);
  int cur = 0;
  for (int k0 = 0; k0 < K; k0 += 64) {
    __syncthreads();
    if (k0 + 64 < K) stage(cur ^ 1, k0 + 64);
#pragma unroll
    for (int kc = 0; kc < 2; ++kc) {
      bf8v av[2], bv[4];
#pragma unroll
      for (int mi = 0; mi < 2; ++mi) {
        int row = wm * 32 + mi * 16 + l15;
        av[mi] = *(const bf8v*)&L.As[cur][row][((kc * 4 + l4) ^ (row & 7)) * 8];
      }
#pragma unroll
      for (int ni = 0; ni < 4; ++ni) {
        int row = wn * 64 + ni * 16 + l15;
        bv[ni] = *(const bf8v*)&L.Bs[cur][row][((kc * 4 + l4) ^ (row & 7)) * 8];
      }
#pragma unroll
      for (int mi = 0; mi < 2; ++mi)
#pragma unroll
        for (int ni = 0; ni < 4; ++ni)
          acc[mi][ni] = __builtin_amdgcn_mfma_f32_16x16x32_bf16(av[mi], bv[ni],
                                                                acc[mi][ni], 0, 0, 0);
    }
    cur ^= 1;
  }

#pragma unroll
  for (int mi = 0; mi < 2; ++mi) {
    int row0 = bm + wm * 32 + mi * 16 + l4 * 4;
#pragma unroll
    for (int ni = 0; ni < 4; ++ni) {
      int col = bn + wn * 64 + ni * 16 + l15;
      float bb = bias[col];
#pragma unroll
      for (int r = 0; r < 4; ++r) {
        int row = row0 + r;
        if (row < M) {
          float v = acc[mi][ni][r] + bb;
          if (relu) v = fmaxf(v, 0.f);
          C[(size_t)row * N + col] = f2bf(v);
        }
      }
    }
  }
}

// ---------------- device split-K GEMM -> f32 partials (8 waves) ------------
__device__ void dev_gemm_sk(const bfu* __restrict__ A, const bfu* __restrict__ Wt,
                            float* __restrict__ Pf, int M, int N, int K,
                            int kbeg, int kend, int bm, int bn, GemmLds& L) {
  int t = threadIdx.x;
  int wave = t >> 6, lane = t & 63;
  int wm = wave >> 1, wn = wave & 1;
  int l15 = lane & 15, l4 = lane >> 4;
  f32x4 acc[2][4];
  f32x4 zz = {0.f, 0.f, 0.f, 0.f};
#pragma unroll
  for (int mi = 0; mi < 2; ++mi)
#pragma unroll
    for (int ni = 0; ni < 4; ++ni) acc[mi][ni] = zz;

  auto stage = [&](int buf, int k0) {
#pragma unroll
    for (int i = 0; i < 2; ++i) {
      int c = t + i * 512;
      int row = c >> 3, kg = c & 7;
      int sc = kg ^ (row & 7);
      if (bm + row < M)
        gl16(A + (size_t)(bm + row) * K + k0 + sc * 8, &L.As[buf][row][kg * 8]);
      gl16(Wt + (size_t)(bn + row) * K + k0 + sc * 8, &L.Bs[buf][row][kg * 8]);
    }
  };
  stage(0, kbeg);
  int cur = 0;
  for (int k0 = kbeg; k0 < kend; k0 += 64) {
    __syncthreads();
    if (k0 + 64 < kend) stage(cur ^ 1, k0 + 64);
#pragma unroll
    for (int kc = 0; kc < 2; ++kc) {
      bf8v av[2], bv[4];
#pragma unroll
      for (int mi = 0; mi < 2; ++mi) {
        int row = wm * 32 + mi * 16 + l15;
        av[mi] = *(const bf8v*)&L.As[cur][row][((kc * 4 + l4) ^ (row & 7)) * 8];
      }
#pragma unroll
      for (int ni = 0; ni < 4; ++ni) {
        int row = wn * 64 + ni * 16 + l15;
        bv[ni] = *(const bf8v*)&L.Bs[cur][row][((kc * 4 + l4) ^ (row & 7)) * 8];
      }
#pragma unroll
      for (int mi = 0; mi < 2; ++mi)
#pragma unroll
        for (int ni = 0; ni < 4; ++ni)
          acc[mi][ni] = __builtin_amdgcn_mfma_f32_16x16x32_bf16(av[mi], bv[ni],
                                                                acc[mi][ni], 0, 0, 0);
    }
    cur ^= 1;
  }

#pragma unroll
  for (int mi = 0; mi < 2; ++mi) {
    int row0 = bm + wm * 32 + mi * 16 + l4 * 4;
#pragma unroll
    for (int ni = 0; ni < 4; ++ni) {
      int col = bn + wn * 64 + ni * 16 + l15;
#pragma unroll
      for (int r = 0; r < 4; ++r) {
        int row = row0 + r;
        if (row < M) Pf[(size_t)row * N + col] = acc[mi][ni][r];
      }
    }
  }
}

// ---------------- device flash attention: 8 waves, 128 q-rows, KVBLK=128 ---
// Wave w owns q-rows [q0 + 16w, q0 + 16w + 16); all waves share K/V tiles.
__device__ void dev_attn(const bfu* __restrict__ Q, int qs,
                         const bfu* __restrict__ Km,
                         const bfu* __restrict__ Vm, int kvs,
                         bfu* __restrict__ O, int Sq, int Sk,
                         int qblk, int h, int b, AttnLds& L) {
  const float scale = 0.125f;
  int q0 = qblk * 128;
  int t = threadIdx.x;
  int wave = t >> 6, lane = t & 63;
  int l15 = lane & 15, l4 = lane >> 4;
  int hoff = h * 64;

  uint4 uq0 = {0u, 0u, 0u, 0u}, uq1 = {0u, 0u, 0u, 0u};
  {
    int qrow = q0 + wave * 16 + l15;
    if (qrow < Sq) {
      const bfu* qp = Q + (size_t)(b * Sq + qrow) * qs + hoff + l4 * 8;
      uq0 = *(const uint4*)qp;
      uq1 = *(const uint4*)(qp + 32);
    }
  }
  bf8v qf0 = *(bf8v*)&uq0, qf1 = *(bf8v*)&uq1;

  float m_[4] = {-1e30f, -1e30f, -1e30f, -1e30f};
  float l_[4] = {0.f, 0.f, 0.f, 0.f};
  f32x4 oacc[4];
  f32x4 zz = {0.f, 0.f, 0.f, 0.f};
#pragma unroll
  for (int n = 0; n < 4; ++n) oacc[n] = zz;

  uint4 ruk[2], ruv[2];
  const uint4 uz = {0u, 0u, 0u, 0u};
  auto load_kv = [&](int k0) {
#pragma unroll
    for (int i = 0; i < 2; ++i) {
      int e = t + i * 512;                 // 0..1023
      int rk = e >> 3, cg = e & 7;         // K: 128 rows x 8 chunks
      ruk[i] = uz;
      if (k0 + rk < Sk)
        ruk[i] = *(const uint4*)(Km + (size_t)(b * Sk + k0 + rk) * kvs + hoff + cg * 8);
      int kv = e & 127, dg = e >> 7;       // V: 128 kv x 8 dgroups
      ruv[i] = uz;
      if (k0 + kv < Sk)
        ruv[i] = *(const uint4*)(Vm + (size_t)(b * Sk + k0 + kv) * kvs + hoff + dg * 8);
    }
  };
  load_kv(0);

  for (int k0 = 0; k0 < Sk; k0 += 128) {
#pragma unroll
    for (int i = 0; i < 2; ++i) {
      int e = t + i * 512;
      int rk = e >> 3, cg = e & 7;
      *(uint4*)&L.Ks[rk][cg * 8] = ruk[i];
      int kv = e & 127, dg = e >> 7;
      bfu vv[8];
      *(uint4*)vv = ruv[i];
#pragma unroll
      for (int j = 0; j < 8; ++j) L.Vt[dg * 8 + j][kv] = vv[j];
    }
    __syncthreads();
    if (k0 + 128 < Sk) load_kv(k0 + 128);

    f32x4 s4[8];
    __builtin_amdgcn_s_setprio(1);
#pragma unroll
    for (int tt = 0; tt < 8; ++tt) {
      bf8v kf0 = *(const bf8v*)&L.Ks[tt * 16 + l15][l4 * 8];
      bf8v kf1 = *(const bf8v*)&L.Ks[tt * 16 + l15][32 + l4 * 8];
      f32x4 a = zz;
      a = __builtin_amdgcn_mfma_f32_16x16x32_bf16(qf0, kf0, a, 0, 0, 0);
      a = __builtin_amdgcn_mfma_f32_16x16x32_bf16(qf1, kf1, a, 0, 0, 0);
      s4[tt] = a;
    }
    __builtin_amdgcn_s_setprio(0);

    bool full = (k0 + 128 <= Sk);
    float f_[4];
#pragma unroll
    for (int r = 0; r < 4; ++r) {
      float sv[8];
      float mx = -1e30f;
      if (full) {
#pragma unroll
        for (int tt = 0; tt < 8; ++tt) {
          float s = s4[tt][r] * scale;
          sv[tt] = s;
          mx = fmaxf(mx, s);
        }
      } else {
#pragma unroll
        for (int tt = 0; tt < 8; ++tt) {
          float s = s4[tt][r] * scale;
          s = (k0 + tt * 16 + l15 < Sk) ? s : -1e30f;
          sv[tt] = s;
          mx = fmaxf(mx, s);
        }
      }
#pragma unroll
      for (int off = 1; off < 16; off <<= 1) mx = fmaxf(mx, __shfl_xor(mx, off));
      float nm = fmaxf(m_[r], mx);
      float f = __expf(m_[r] - nm);
      float ps = 0.f;
#pragma unroll
      for (int tt = 0; tt < 8; ++tt) {
        float p = __expf(sv[tt] - nm);
        ps += p;
        L.Sm[wave][l4 * 4 + r][tt * 16 + l15] = f2bf(p);
      }
#pragma unroll
      for (int off = 1; off < 16; off <<= 1) ps += __shfl_xor(ps, off);
      l_[r] = l_[r] * f + ps;
      m_[r] = nm;
      f_[r] = f;
    }
#pragma unroll
    for (int n = 0; n < 4; ++n)
#pragma unroll
      for (int r = 0; r < 4; ++r) oacc[n][r] *= f_[r];

    __builtin_amdgcn_s_setprio(1);
#pragma unroll
    for (int h2 = 0; h2 < 2; ++h2) {
      bf8v p0 = *(const bf8v*)&L.Sm[wave][l15][h2 * 64 + l4 * 8];
      bf8v p1 = *(const bf8v*)&L.Sm[wave][l15][h2 * 64 + 32 + l4 * 8];
#pragma unroll
      for (int n = 0; n < 4; ++n) {
        bf8v v0 = *(const bf8v*)&L.Vt[n * 16 + l15][h2 * 64 + l4 * 8];
        bf8v v1 = *(const bf8v*)&L.Vt[n * 16 + l15][h2 * 64 + 32 + l4 * 8];
        oacc[n] = __builtin_amdgcn_mfma_f32_16x16x32_bf16(p0, v0, oacc[n], 0, 0, 0);
        oacc[n] = __builtin_amdgcn_mfma_f32_16x16x32_bf16(p1, v1, oacc[n], 0, 0, 0);
      }
    }
    __builtin_amdgcn_s_setprio(0);
    __syncthreads();
  }

#pragma unroll
  for (int r = 0; r < 4; ++r) {
    int row = q0 + wave * 16 + l4 * 4 + r;
    if (row < Sq) {
      float inv = 1.f / l_[r];
#pragma unroll
      for (int n = 0; n < 4; ++n)
        O[(size_t)(b * Sq + row) * 512 + hoff + n * 16 + l15] = f2bf(oacc[n][r] * inv);
    }
  }
}

// ---------------- device LN(A + sum_z P[z] + bias), fused epilogues --------
__device__ void dev_ln_red(const float* __restrict__ A, const float* __restrict__ P,
                           int nsplit, size_t pz, const float* __restrict__ bias,
                           const float* __restrict__ g, const float* __restrict__ be,
                           float* __restrict__ of, bfu* __restrict__ ob,
                           const float* __restrict__ add2, int qe_mode,
                           float* __restrict__ of2, bfu* __restrict__ ob2,
                           int rows, int tile) {
  int row = tile * 4 + (threadIdx.x >> 6);
  int lane = threadIdx.x & 63;
  if (row < rows) {
    const float* pa = A + (size_t)row * 512;
    float v[8];
    float s = 0.f, s2 = 0.f;
#pragma unroll
    for (int j = 0; j < 8; ++j) {
      int c = lane + j * 64;
      float x = pa[c] + bias[c];
      for (int z = 0; z < nsplit; ++z) x += P[z * pz + (size_t)row * 512 + c];
      v[j] = x; s += x; s2 += x * x;
    }
#pragma unroll
    for (int off = 32; off > 0; off >>= 1) {
      s += __shfl_xor(s, off);
      s2 += __shfl_xor(s2, off);
    }
    float mean = s * (1.f / 512.f);
    float var = s2 * (1.f / 512.f) - mean * mean;
    float r = rsqrtf(var + 1e-5f);
    int arow = qe_mode ? (row % 100) : row;
#pragma unroll
    for (int j = 0; j < 8; ++j) {
      int c = lane + j * 64;
      float o = (v[j] - mean) * r * g[c] + be[c];
      if (of) of[(size_t)row * 512 + c] = o;
      if (ob) ob[(size_t)row * 512 + c] = f2bf(o);
      if (add2) {
        float o2 = o + add2[(size_t)arow * 512 + c];
        if (of2) of2[(size_t)row * 512 + c] = o2;
        if (ob2) ob2[(size_t)row * 512 + c] = f2bf(o2);
      }
    }
  }
}

// ---------------- standalone kernels ----------------------------------------
__global__ __launch_bounds__(512) void k_gemm_bf(const bfu* __restrict__ A,
                                                 const bfu* __restrict__ Wt,
                                                 const float* __restrict__ bias,
                                                 bfu* __restrict__ C,
                                                 int M, int N, int K, int relu,
                                                 size_t wtz, size_t cz, int bz) {
  __shared__ GemmLds L;
  int nwg = gridDim.x * gridDim.y * gridDim.z;
  int flat = blockIdx.x + gridDim.x * (blockIdx.y + gridDim.y * blockIdx.z);
  int s = xcd_swz(flat, nwg);
  int bx = s % gridDim.x; s /= gridDim.x;
  int by = s % gridDim.y;
  int bz2 = s / gridDim.y;
  dev_gemm(A, Wt + (size_t)bz2 * wtz, bias + bz2 * bz, C + (size_t)bz2 * cz,
           M, N, K, relu, by * 128, bx * 128, L);
}

__global__ __launch_bounds__(512) void k_gemm_sk(const bfu* __restrict__ A,
                                                 const bfu* __restrict__ Wt,
                                                 float* __restrict__ Pf,
                                                 int M, int N, int K, int ksplit) {
  __shared__ GemmLds L;
  int nwg = gridDim.x * gridDim.y * gridDim.z;
  int flat = blockIdx.x + gridDim.x * (blockIdx.y + gridDim.y * blockIdx.z);
  int s = xcd_swz(flat, nwg);
  int bx = s % gridDim.x; s /= gridDim.x;
  int by = s % gridDim.y;
  int z = s / gridDim.y;
  int Kc = K / ksplit;
  dev_gemm_sk(A, Wt, Pf + (size_t)z * M * N, M, N, K, z * Kc, z * Kc + Kc,
              by * 128, bx * 128, L);
}

__global__ __launch_bounds__(512) void k_attn_mfma(const bfu* __restrict__ Q, int qs,
                                                   const bfu* __restrict__ Km,
                                                   const bfu* __restrict__ Vm, int kvs,
                                                   bfu* __restrict__ O,
                                                   int Sq, int Sk) {
  __shared__ AttnLds L;
  int nwg = gridDim.x * gridDim.y * gridDim.z;
  int flat = blockIdx.x + gridDim.x * (blockIdx.y + gridDim.y * blockIdx.z);
  int s = xcd_swz(flat, nwg);
  int qblk = s % gridDim.x; s /= gridDim.x;
  int h = s % gridDim.y;
  int b = s / gridDim.y;
  dev_attn(Q, qs, Km, Vm, kvs, O, Sq, Sk, qblk, h, b, L);
}

__global__ __launch_bounds__(256) void k_ln_red(const float* __restrict__ A,
                                                const float* __restrict__ P,
                                                int nsplit, size_t pz,
                                                const float* __restrict__ bias,
                                                const float* __restrict__ g,
                                                const float* __restrict__ be,
                                                float* __restrict__ of,
                                                bfu* __restrict__ ob,
                                                const float* __restrict__ add2,
                                                int qe_mode,
                                                float* __restrict__ of2,
                                                bfu* __restrict__ ob2,
                                                int rows) {
  dev_ln_red(A, P, nsplit, pz, bias, g, be, of, ob, add2, qe_mode, of2, ob2,
             rows, blockIdx.x);
}

__global__ __launch_bounds__(256) void k_transpose2(const float* __restrict__ s0,
                                                    const float* __restrict__ s1,
                                                    float* __restrict__ d0,
                                                    float* __restrict__ d1) {
  __shared__ float tile[32][33];
  int zz = blockIdx.z;
  const float* in = (zz < 4) ? s0 : s1;
  float* out = (zz < 4) ? d0 : d1;
  int b = zz & 3;
  int c0 = blockIdx.x * 32, s0i = blockIdx.y * 32;
  int tx = threadIdx.x, ty = threadIdx.y;
  for (int i = ty; i < 32; i += 8)
    tile[i][tx] = in[((size_t)(b * 512 + c0 + i)) * 1024 + s0i + tx];
  __syncthreads();
  for (int i = ty; i < 32; i += 8)
    out[((size_t)(b * 1024 + s0i + i)) * 512 + c0 + tx] = tile[tx][i];
}

__global__ __launch_bounds__(256) void k_wt3(const float* __restrict__ s0,
                                             const float* __restrict__ s1,
                                             const float* __restrict__ s2,
                                             bfu* __restrict__ dst,
                                             int K, int N, int per) {
  __shared__ bfu tile[32][33];
  int g = blockIdx.z;
  const float* sb = (g < per) ? s0 : (g < 2 * per) ? s1 : s2;
  int gl = (g < per) ? g : (g < 2 * per) ? (g - per) : (g - 2 * per);
  const float* s = sb + (size_t)gl * (size_t)K * N;
  bfu* d = dst + (size_t)g * (size_t)K * N;
  int n0 = blockIdx.x * 32, k0 = blockIdx.y * 32;
  int tx = threadIdx.x, ty = threadIdx.y;
  for (int i = ty; i < 32; i += 8)
    tile[i][tx] = f2bf(s[(size_t)(k0 + i) * N + n0 + tx]);
  __syncthreads();
  for (int i = ty; i < 32; i += 8)
    d[(size_t)(n0 + i) * K + k0 + tx] = tile[tx][i];
}

__global__ void k_add_dual(const float* __restrict__ a, const float* __restrict__ b,
                           float* __restrict__ of, bfu* __restrict__ ob, int n4) {
  int i = blockIdx.x * blockDim.x + threadIdx.x;
  if (i >= n4) return;
  float4 x = ((const float4*)a)[i];
  float4 y = ((const float4*)b)[i];
  float4 r = make_float4(x.x + y.x, x.y + y.y, x.z + y.z, x.w + y.w);
  ((float4*)of)[i] = r;
  ((ushort4*)ob)[i] = make_ushort4(f2bf(r.x), f2bf(r.y), f2bf(r.z), f2bf(r.w));
}

__global__ void k_qe0(const float* __restrict__ qe, float* __restrict__ of,
                      bfu* __restrict__ ob) {
  int i = blockIdx.x * blockDim.x + threadIdx.x;
  if (i >= 51200) return;
  int row = i >> 7;
  int q = row % 100;
  int c4 = i & 127;
  float4 y = ((const float4*)qe)[q * 128 + c4];
  ((float4*)of)[i] = y;
  ((ushort4*)ob)[i] = make_ushort4(f2bf(y.x), f2bf(y.y), f2bf(y.z), f2bf(y.w));
}

// ---------------------------------------------------------------------------

extern "C" void kernel_launch(void* const* d_in, const int* in_sizes, int n_in,
                              void* d_out, int out_size, void* d_ws, size_t ws_size,
                              hipStream_t stream) {
  const float* src         = (const float*)d_in[0];
  const float* query_embed = (const float*)d_in[1];
  const float* pos_embed   = (const float*)d_in[2];
  const float* enc_attn_w  = (const float*)d_in[3];
  const float* enc_attn_b  = (const float*)d_in[4];
  const float* enc_w1      = (const float*)d_in[5];
  const float* enc_b1      = (const float*)d_in[6];
  const float* enc_w2      = (const float*)d_in[7];
  const float* enc_b2      = (const float*)d_in[8];
  const float* enc_ln_w    = (const float*)d_in[9];
  const float* enc_ln_b    = (const float*)d_in[10];
  const float* dec_sa_w    = (const float*)d_in[11];
  const float* dec_sa_b    = (const float*)d_in[12];
  const float* dec_ca_w    = (const float*)d_in[13];
  const float* dec_ca_b    = (const float*)d_in[14];
  const float* dec_w1      = (const float*)d_in[15];
  const float* dec_b1      = (const float*)d_in[16];
  const float* dec_w2      = (const float*)d_in[17];
  const float* dec_b2      = (const float*)d_in[18];
  const float* dec_ln_w    = (const float*)d_in[19];
  const float* dec_ln_b    = (const float*)d_in[20];
  float* out = (float*)d_out;

  const size_t ENC = 4UL * 1024 * 512;
  const size_t DEC = 4UL * 100 * 512;
  const size_t MAT = 512UL * 512;

  float* p = (float*)d_ws;
  float* x    = p; p += ENC;
  float* pos  = p; p += ENC;
  float* t1   = p; p += ENC;
  float* t2   = p; p += ENC;
  float* t3   = p; p += DEC;
  float* Pf   = p; p += 4 * ENC;   // split-K f32 partials

  bfu* bp = (bfu*)p;
  bfu* t1b    = bp; bp += ENC;
  bfu* t2b    = bp; bp += ENC;
  bfu* t3b    = bp; bp += DEC;
  bfu* qkvb   = bp; bp += 4096UL * 1536;
  bfu* aob    = bp; bp += ENC;
  bfu* hbb    = bp; bp += 4096UL * 2048;
  bfu* meminb = bp; bp += ENC;
  bfu* ckvb   = bp; bp += 6UL * 4096 * 1024;
  bfu* att_all_t = bp; bp += 72 * MAT;
  bfu* w1_all_t  = bp; bp += 12UL * 512 * 2048;
  bfu* w2_all_t  = bp; bp += 12UL * 2048 * 512;
  bfu* enc_att_t = att_all_t;
  bfu* dsa_t     = att_all_t + 24 * MAT;
  bfu* dca_t     = att_all_t + 48 * MAT;
  bfu* enc_w1t   = w1_all_t;
  bfu* dw1t      = w1_all_t + 6UL * 512 * 2048;
  bfu* enc_w2t   = w2_all_t;
  bfu* dw2t      = w2_all_t + 6UL * 2048 * 512;

  dim3 tb(32, 8);
  k_transpose2<<<dim3(16, 32, 8), tb, 0, stream>>>(src, pos_embed, x, pos);

  k_wt3<<<dim3(16, 16, 72), tb, 0, stream>>>(enc_attn_w, dec_sa_w, dec_ca_w,
                                             att_all_t, 512, 512, 24);
  k_wt3<<<dim3(64, 16, 12), tb, 0, stream>>>(enc_w1, dec_w1, dec_w1,
                                             w1_all_t, 512, 2048, 6);
  k_wt3<<<dim3(16, 64, 12), tb, 0, stream>>>(enc_w2, dec_w2, dec_w2,
                                             w2_all_t, 2048, 512, 6);

  // ----------------------------- encoder ----------------------------------
  k_add_dual<<<2048, 256, 0, stream>>>(x, pos, t1, t1b, (int)(ENC / 4));
  for (int l = 0; l < 6; ++l) {
    const bfu* awt = enc_att_t + (size_t)l * 4 * MAT;
    const float* ab = enc_attn_b + (size_t)l * 2048;
    k_gemm_bf<<<dim3(12, 32), 512, 0, stream>>>(t1b, awt, ab,
                                                qkvb, 4096, 1536, 512, 0, 0, 0, 0);
    k_attn_mfma<<<dim3(8, 8, 4), 512, 0, stream>>>(qkvb, 1536, qkvb + 512, qkvb + 1024, 1536,
                                                   aob, 1024, 1024);
    k_gemm_sk<<<dim3(4, 32, 2), 512, 0, stream>>>(aob, awt + 3 * MAT, Pf,
                                                  4096, 512, 512, 2);
    k_ln_red<<<1024, 256, 0, stream>>>(t1, Pf, 2, ENC, ab + 1536,
                                       enc_ln_w + (size_t)(l * 2 + 0) * 512,
                                       enc_ln_b + (size_t)(l * 2 + 0) * 512,
                                       t2, t2b, (const float*)nullptr, 0,
                                       (float*)nullptr, (bfu*)nullptr, 4096);
    k_gemm_bf<<<dim3(16, 32), 512, 0, stream>>>(t2b, enc_w1t + (size_t)l * 512 * 2048,
                                                enc_b1 + (size_t)l * 2048, hbb,
                                                4096, 2048, 512, 1, 0, 0, 0);
    k_gemm_sk<<<dim3(4, 32, 4), 512, 0, stream>>>(hbb, enc_w2t + (size_t)l * 2048 * 512, Pf,
                                                  4096, 512, 2048, 4);
    if (l < 5) {
      k_ln_red<<<1024, 256, 0, stream>>>(t2, Pf, 4, ENC, enc_b2 + (size_t)l * 512,
                                         enc_ln_w + (size_t)(l * 2 + 1) * 512,
                                         enc_ln_b + (size_t)(l * 2 + 1) * 512,
                                         (float*)nullptr, (bfu*)nullptr,
                                         pos, 0, t1, t1b, 4096);
    } else {
      k_ln_red<<<1024, 256, 0, stream>>>(t2, Pf, 4, ENC, enc_b2 + (size_t)l * 512,
                                         enc_ln_w + (size_t)(l * 2 + 1) * 512,
                                         enc_ln_b + (size_t)(l * 2 + 1) * 512,
                                         out + DEC, (bfu*)nullptr,
                                         pos, 0, (float*)nullptr, meminb, 4096);
    }
  }

  // all 6 decoder layers' cross-attn K/V projections in one dispatch
  k_gemm_bf<<<dim3(8, 32, 6), 512, 0, stream>>>(meminb, dca_t + MAT, dec_ca_b + 512,
                                                ckvb, 4096, 1024, 512, 0,
                                                4 * MAT, 4096UL * 1024, 2048);

  // ----------------------------- decoder ----------------------------------
  k_qe0<<<200, 256, 0, stream>>>(query_embed, t1, t1b);
  for (int l = 0; l < 6; ++l) {
    const bfu* swt = dsa_t + (size_t)l * 4 * MAT;
    const bfu* cwt = dca_t + (size_t)l * 4 * MAT;
    const float* sb = dec_sa_b + (size_t)l * 2048;
    const float* cb = dec_ca_b + (size_t)l * 2048;
    // self-attention
    k_gemm_bf<<<dim3(12, 4), 512, 0, stream>>>(t1b, swt, sb,
                                               qkvb, 400, 1536, 512, 0, 0, 0, 0);
    k_attn_mfma<<<dim3(1, 8, 4), 512, 0, stream>>>(qkvb, 1536, qkvb + 512, qkvb + 1024, 1536,
                                                   aob, 100, 100);
    k_gemm_sk<<<dim3(4, 4, 2), 512, 0, stream>>>(aob, swt + 3 * MAT, Pf,
                                                 400, 512, 512, 2);
    k_ln_red<<<100, 256, 0, stream>>>(t1, Pf, 2, 400UL * 512, sb + 1536,
                                      dec_ln_w + (size_t)(l * 3 + 0) * 512,
                                      dec_ln_b + (size_t)(l * 3 + 0) * 512,
                                      t2, t2b, (const float*)nullptr, 0,
                                      (float*)nullptr, (bfu*)nullptr, 400);
    // cross-attention
    k_gemm_bf<<<dim3(4, 4), 512, 0, stream>>>(t2b, cwt, cb,
                                              qkvb, 400, 512, 512, 0, 0, 0, 0);
    k_attn_mfma<<<dim3(1, 8, 4), 512, 0, stream>>>(qkvb, 512,
                                                   ckvb + (size_t)l * 4096 * 1024,
                                                   ckvb + (size_t)l * 4096 * 1024 + 512, 1024,
                                                   aob, 100, 1024);
    k_gemm_sk<<<dim3(4, 4, 2), 512, 0, stream>>>(aob, cwt + 3 * MAT, Pf,
                                                 400, 512, 512, 2);
    k_ln_red<<<100, 256, 0, stream>>>(t2, Pf, 2, 400UL * 512, cb + 1536,
                                      dec_ln_w + (size_t)(l * 3 + 1) * 512,
                                      dec_ln_b + (size_t)(l * 3 + 1) * 512,
                                      t3, t3b, (const float*)nullptr, 0,
                                      (float*)nullptr, (bfu*)nullptr, 400);
    // ffn
    k_gemm_bf<<<dim3(16, 4), 512, 0, stream>>>(t3b, dw1t + (size_t)l * 512 * 2048,
                                               dec_b1 + (size_t)l * 2048, hbb,
                                               400, 2048, 512, 1, 0, 0, 0);
    k_gemm_sk<<<dim3(4, 4, 4), 512, 0, stream>>>(hbb, dw2t + (size_t)l * 2048 * 512, Pf,
                                                 400, 512, 2048, 4);
    if (l < 5) {
      k_ln_red<<<100, 256, 0, stream>>>(t3, Pf, 4, 400UL * 512, dec_b2 + (size_t)l * 512,
                                        dec_ln_w + (size_t)(l * 3 + 2) * 512,
                                        dec_ln_b + (size_t)(l * 3 + 2) * 512,
                                        (float*)nullptr, (bfu*)nullptr,
                                        query_embed, 1, t1, t1b, 400);
    } else {
      k_ln_red<<<100, 256, 0, stream>>>(t3, Pf, 4, 400UL * 512, dec_b2 + (size_t)l * 512,
                                        dec_ln_w + (size_t)(l * 3 + 2) * 512,
                                        dec_ln_b + (size_t)(l * 3 + 2) * 512,
                                        out, (bfu*)nullptr, (const float*)nullptr, 0,
                                        (float*)nullptr, (bfu*)nullptr, 400);
    }
  }
}

// Round 21
// 1681.095 us; speedup vs baseline: 1.1395x; 1.0100x over previous
//
#include <hip/hip_runtime.h>
#include <math.h>

// ---------------------------------------------------------------------------
// DETR-style transformer. bf16 MFMA GEMMs (1024-thread/16-wave blocks,
// global_load_lds, BK=64 2-phase dbuf, XOR-swizzled LDS, XCD block swizzle)
// + bf16 MFMA flash attention (512-thread/8-wave, 128 q-rows, KVBLK=128,
// setprio). Split-K GEMMs -> f32 partials; k_ln_red fuses
// reduce+bias+residual+LN+re-add.
// B=4, S=1024, NQ=100, D=512, H=8, dk=64, FF=2048, L=6
// ---------------------------------------------------------------------------

typedef unsigned short bfu;
typedef unsigned int u32;
typedef __bf16 bf8v __attribute__((ext_vector_type(8)));
typedef float f32x4 __attribute__((ext_vector_type(4)));

__device__ inline bfu f2bf(float f) {
  union { float f; u32 u; } v; v.f = f;
  u32 u = v.u;
  u32 r = (u + 0x7fffu + ((u >> 16) & 1u)) >> 16;
  return (bfu)r;
}
__device__ inline float bflo(u32 u) { return __uint_as_float(u << 16); }

typedef const __attribute__((address_space(1))) u32 gas_t;
typedef __attribute__((address_space(3))) u32 las_t;
__device__ __forceinline__ void gl16(const void* g, void* l) {
  __builtin_amdgcn_global_load_lds((gas_t*)g, (las_t*)l, 16, 0, 0);
}

// bijective XCD swizzle (m204): consecutive logical tiles -> same XCD chunk
__device__ __forceinline__ int xcd_swz(int flat, int nwg) {
  int q = nwg >> 3, r = nwg & 7;
  int xcd = flat & 7, idx = flat >> 3;
  return (xcd < r ? xcd * (q + 1) : r * (q + 1) + (xcd - r) * q) + idx;
}

struct GemmLds { bfu As[2][128][64]; bfu Bs[2][128][64]; };      // 64 KB
struct AttnLds { bfu Ks[128][72]; bfu Vt[64][136]; bfu Sm[8][16][136]; };  // ~70 KB

// ---------------- device GEMM body: 16 waves, BK=64, gl_lds, 2-phase dbuf --
// Wave w (0..15): wm=w>>1 (0..7) -> 16 C-rows; wn=w&1 -> 64 C-cols.
__device__ void dev_gemm(const bfu* __restrict__ A, const bfu* __restrict__ Wt,
                         const float* __restrict__ bias, bfu* __restrict__ C,
                         int M, int N, int K, int relu, int bm, int bn,
                         GemmLds& L) {
  int t = threadIdx.x;
  int wave = t >> 6, lane = t & 63;
  int wm = wave >> 1, wn = wave & 1;
  int l15 = lane & 15, l4 = lane >> 4;
  f32x4 acc[4];
  f32x4 zz = {0.f, 0.f, 0.f, 0.f};
#pragma unroll
  for (int ni = 0; ni < 4; ++ni) acc[ni] = zz;

  auto stage = [&](int buf, int k0) {
    int c = t;                        // 0..1023 chunks of 16B
    int row = c >> 3, kg = c & 7;
    int sc = kg ^ (row & 7);
    if (bm + row < M)
      gl16(A + (size_t)(bm + row) * K + k0 + sc * 8, &L.As[buf][row][kg * 8]);
    gl16(Wt + (size_t)(bn + row) * K + k0 + sc * 8, &L.Bs[buf][row][kg * 8]);
  };
  stage(0, 0);
  int cur = 0;
  for (int k0 = 0; k0 < K; k0 += 64) {
    __syncthreads();
    if (k0 + 64 < K) stage(cur ^ 1, k0 + 64);
#pragma unroll
    for (int kc = 0; kc < 2; ++kc) {
      int rowA = wm * 16 + l15;
      bf8v av = *(const bf8v*)&L.As[cur][rowA][((kc * 4 + l4) ^ (rowA & 7)) * 8];
      bf8v bv[4];
#pragma unroll
      for (int ni = 0; ni < 4; ++ni) {
        int row = wn * 64 + ni * 16 + l15;
        bv[ni] = *(const bf8v*)&L.Bs[cur][row][((kc * 4 + l4) ^ (row & 7)) * 8];
      }
#pragma unroll
      for (int ni = 0; ni < 4; ++ni)
        acc[ni] = __builtin_amdgcn_mfma_f32_16x16x32_bf16(av, bv[ni], acc[ni], 0, 0, 0);
    }
    cur ^= 1;
  }

  int row0 = bm + wm * 16 + l4 * 4;
#pragma unroll
  for (int ni = 0; ni < 4; ++ni) {
    int col = bn + wn * 64 + ni * 16 + l15;
    float bb = bias[col];
#pragma unroll
    for (int r = 0; r < 4; ++r) {
      int row = row0 + r;
      if (row < M) {
        float v = acc[ni][r] + bb;
        if (relu) v = fmaxf(v, 0.f);
        C[(size_t)row * N + col] = f2bf(v);
      }
    }
  }
}

// ---------------- device split-K GEMM -> f32 partials (16 waves) -----------
__device__ void dev_gemm_sk(const bfu* __restrict__ A, const bfu* __restrict__ Wt,
                            float* __restrict__ Pf, int M, int N, int K,
                            int kbeg, int kend, int bm, int bn, GemmLds& L) {
  int t = threadIdx.x;
  int wave = t >> 6, lane = t & 63;
  int wm = wave >> 1, wn = wave & 1;
  int l15 = lane & 15, l4 = lane >> 4;
  f32x4 acc[4];
  f32x4 zz = {0.f, 0.f, 0.f, 0.f};
#pragma unroll
  for (int ni = 0; ni < 4; ++ni) acc[ni] = zz;

  auto stage = [&](int buf, int k0) {
    int c = t;
    int row = c >> 3, kg = c & 7;
    int sc = kg ^ (row & 7);
    if (bm + row < M)
      gl16(A + (size_t)(bm + row) * K + k0 + sc * 8, &L.As[buf][row][kg * 8]);
    gl16(Wt + (size_t)(bn + row) * K + k0 + sc * 8, &L.Bs[buf][row][kg * 8]);
  };
  stage(0, kbeg);
  int cur = 0;
  for (int k0 = kbeg; k0 < kend; k0 += 64) {
    __syncthreads();
    if (k0 + 64 < kend) stage(cur ^ 1, k0 + 64);
#pragma unroll
    for (int kc = 0; kc < 2; ++kc) {
      int rowA = wm * 16 + l15;
      bf8v av = *(const bf8v*)&L.As[cur][rowA][((kc * 4 + l4) ^ (rowA & 7)) * 8];
      bf8v bv[4];
#pragma unroll
      for (int ni = 0; ni < 4; ++ni) {
        int row = wn * 64 + ni * 16 + l15;
        bv[ni] = *(const bf8v*)&L.Bs[cur][row][((kc * 4 + l4) ^ (row & 7)) * 8];
      }
#pragma unroll
      for (int ni = 0; ni < 4; ++ni)
        acc[ni] = __builtin_amdgcn_mfma_f32_16x16x32_bf16(av, bv[ni], acc[ni], 0, 0, 0);
    }
    cur ^= 1;
  }

  int row0 = bm + wm * 16 + l4 * 4;
#pragma unroll
  for (int ni = 0; ni < 4; ++ni) {
    int col = bn + wn * 64 + ni * 16 + l15;
#pragma unroll
    for (int r = 0; r < 4; ++r) {
      int row = row0 + r;
      if (row < M) Pf[(size_t)row * N + col] = acc[ni][r];
    }
  }
}

// ---------------- device flash attention: 8 waves, 128 q-rows, KVBLK=128 ---
__device__ void dev_attn(const bfu* __restrict__ Q, int qs,
                         const bfu* __restrict__ Km,
                         const bfu* __restrict__ Vm, int kvs,
                         bfu* __restrict__ O, int Sq, int Sk,
                         int qblk, int h, int b, AttnLds& L) {
  const float scale = 0.125f;
  int q0 = qblk * 128;
  int t = threadIdx.x;
  int wave = t >> 6, lane = t & 63;
  int l15 = lane & 15, l4 = lane >> 4;
  int hoff = h * 64;

  uint4 uq0 = {0u, 0u, 0u, 0u}, uq1 = {0u, 0u, 0u, 0u};
  {
    int qrow = q0 + wave * 16 + l15;
    if (qrow < Sq) {
      const bfu* qp = Q + (size_t)(b * Sq + qrow) * qs + hoff + l4 * 8;
      uq0 = *(const uint4*)qp;
      uq1 = *(const uint4*)(qp + 32);
    }
  }
  bf8v qf0 = *(bf8v*)&uq0, qf1 = *(bf8v*)&uq1;

  float m_[4] = {-1e30f, -1e30f, -1e30f, -1e30f};
  float l_[4] = {0.f, 0.f, 0.f, 0.f};
  f32x4 oacc[4];
  f32x4 zz = {0.f, 0.f, 0.f, 0.f};
#pragma unroll
  for (int n = 0; n < 4; ++n) oacc[n] = zz;

  uint4 ruk[2], ruv[2];
  const uint4 uz = {0u, 0u, 0u, 0u};
  auto load_kv = [&](int k0) {
#pragma unroll
    for (int i = 0; i < 2; ++i) {
      int e = t + i * 512;
      int rk = e >> 3, cg = e & 7;
      ruk[i] = uz;
      if (k0 + rk < Sk)
        ruk[i] = *(const uint4*)(Km + (size_t)(b * Sk + k0 + rk) * kvs + hoff + cg * 8);
      int kv = e & 127, dg = e >> 7;
      ruv[i] = uz;
      if (k0 + kv < Sk)
        ruv[i] = *(const uint4*)(Vm + (size_t)(b * Sk + k0 + kv) * kvs + hoff + dg * 8);
    }
  };
  load_kv(0);

  for (int k0 = 0; k0 < Sk; k0 += 128) {
#pragma unroll
    for (int i = 0; i < 2; ++i) {
      int e = t + i * 512;
      int rk = e >> 3, cg = e & 7;
      *(uint4*)&L.Ks[rk][cg * 8] = ruk[i];
      int kv = e & 127, dg = e >> 7;
      bfu vv[8];
      *(uint4*)vv = ruv[i];
#pragma unroll
      for (int j = 0; j < 8; ++j) L.Vt[dg * 8 + j][kv] = vv[j];
    }
    __syncthreads();
    if (k0 + 128 < Sk) load_kv(k0 + 128);

    f32x4 s4[8];
    __builtin_amdgcn_s_setprio(1);
#pragma unroll
    for (int tt = 0; tt < 8; ++tt) {
      bf8v kf0 = *(const bf8v*)&L.Ks[tt * 16 + l15][l4 * 8];
      bf8v kf1 = *(const bf8v*)&L.Ks[tt * 16 + l15][32 + l4 * 8];
      f32x4 a = zz;
      a = __builtin_amdgcn_mfma_f32_16x16x32_bf16(qf0, kf0, a, 0, 0, 0);
      a = __builtin_amdgcn_mfma_f32_16x16x32_bf16(qf1, kf1, a, 0, 0, 0);
      s4[tt] = a;
    }
    __builtin_amdgcn_s_setprio(0);

    bool full = (k0 + 128 <= Sk);
    float f_[4];
#pragma unroll
    for (int r = 0; r < 4; ++r) {
      float sv[8];
      float mx = -1e30f;
      if (full) {
#pragma unroll
        for (int tt = 0; tt < 8; ++tt) {
          float s = s4[tt][r] * scale;
          sv[tt] = s;
          mx = fmaxf(mx, s);
        }
      } else {
#pragma unroll
        for (int tt = 0; tt < 8; ++tt) {
          float s = s4[tt][r] * scale;
          s = (k0 + tt * 16 + l15 < Sk) ? s : -1e30f;
          sv[tt] = s;
          mx = fmaxf(mx, s);
        }
      }
#pragma unroll
      for (int off = 1; off < 16; off <<= 1) mx = fmaxf(mx, __shfl_xor(mx, off));
      float nm = fmaxf(m_[r], mx);
      float f = __expf(m_[r] - nm);
      float ps = 0.f;
#pragma unroll
      for (int tt = 0; tt < 8; ++tt) {
        float p = __expf(sv[tt] - nm);
        ps += p;
        L.Sm[wave][l4 * 4 + r][tt * 16 + l15] = f2bf(p);
      }
#pragma unroll
      for (int off = 1; off < 16; off <<= 1) ps += __shfl_xor(ps, off);
      l_[r] = l_[r] * f + ps;
      m_[r] = nm;
      f_[r] = f;
    }
#pragma unroll
    for (int n = 0; n < 4; ++n)
#pragma unroll
      for (int r = 0; r < 4; ++r) oacc[n][r] *= f_[r];

    __builtin_amdgcn_s_setprio(1);
#pragma unroll
    for (int h2 = 0; h2 < 2; ++h2) {
      bf8v p0 = *(const bf8v*)&L.Sm[wave][l15][h2 * 64 + l4 * 8];
      bf8v p1 = *(const bf8v*)&L.Sm[wave][l15][h2 * 64 + 32 + l4 * 8];
#pragma unroll
      for (int n = 0; n < 4; ++n) {
        bf8v v0 = *(const bf8v*)&L.Vt[n * 16 + l15][h2 * 64 + l4 * 8];
        bf8v v1 = *(const bf8v*)&L.Vt[n * 16 + l15][h2 * 64 + 32 + l4 * 8];
        oacc[n] = __builtin_amdgcn_mfma_f32_16x16x32_bf16(p0, v0, oacc[n], 0, 0, 0);
        oacc[n] = __builtin_amdgcn_mfma_f32_16x16x32_bf16(p1, v1, oacc[n], 0, 0, 0);
      }
    }
    __builtin_amdgcn_s_setprio(0);
    __syncthreads();
  }

#pragma unroll
  for (int r = 0; r < 4; ++r) {
    int row = q0 + wave * 16 + l4 * 4 + r;
    if (row < Sq) {
      float inv = 1.f / l_[r];
#pragma unroll
      for (int n = 0; n < 4; ++n)
        O[(size_t)(b * Sq + row) * 512 + hoff + n * 16 + l15] = f2bf(oacc[n][r] * inv);
    }
  }
}

// ---------------- device LN(A + sum_z P[z] + bias), fused epilogues --------
__device__ void dev_ln_red(const float* __restrict__ A, const float* __restrict__ P,
                           int nsplit, size_t pz, const float* __restrict__ bias,
                           const float* __restrict__ g, const float* __restrict__ be,
                           float* __restrict__ of, bfu* __restrict__ ob,
                           const float* __restrict__ add2, int qe_mode,
                           float* __restrict__ of2, bfu* __restrict__ ob2,
                           int rows, int tile) {
  int row = tile * 4 + (threadIdx.x >> 6);
  int lane = threadIdx.x & 63;
  if (row < rows) {
    const float* pa = A + (size_t)row * 512;
    float v[8];
    float s = 0.f, s2 = 0.f;
#pragma unroll
    for (int j = 0; j < 8; ++j) {
      int c = lane + j * 64;
      float x = pa[c] + bias[c];
      for (int z = 0; z < nsplit; ++z) x += P[z * pz + (size_t)row * 512 + c];
      v[j] = x; s += x; s2 += x * x;
    }
#pragma unroll
    for (int off = 32; off > 0; off >>= 1) {
      s += __shfl_xor(s, off);
      s2 += __shfl_xor(s2, off);
    }
    float mean = s * (1.f / 512.f);
    float var = s2 * (1.f / 512.f) - mean * mean;
    float r = rsqrtf(var + 1e-5f);
    int arow = qe_mode ? (row % 100) : row;
#pragma unroll
    for (int j = 0; j < 8; ++j) {
      int c = lane + j * 64;
      float o = (v[j] - mean) * r * g[c] + be[c];
      if (of) of[(size_t)row * 512 + c] = o;
      if (ob) ob[(size_t)row * 512 + c] = f2bf(o);
      if (add2) {
        float o2 = o + add2[(size_t)arow * 512 + c];
        if (of2) of2[(size_t)row * 512 + c] = o2;
        if (ob2) ob2[(size_t)row * 512 + c] = f2bf(o2);
      }
    }
  }
}

// ---------------- standalone kernels ----------------------------------------
__global__ __launch_bounds__(1024) void k_gemm_bf(const bfu* __restrict__ A,
                                                  const bfu* __restrict__ Wt,
                                                  const float* __restrict__ bias,
                                                  bfu* __restrict__ C,
                                                  int M, int N, int K, int relu,
                                                  size_t wtz, size_t cz, int bz) {
  __shared__ GemmLds L;
  int nwg = gridDim.x * gridDim.y * gridDim.z;
  int flat = blockIdx.x + gridDim.x * (blockIdx.y + gridDim.y * blockIdx.z);
  int s = xcd_swz(flat, nwg);
  int bx = s % gridDim.x; s /= gridDim.x;
  int by = s % gridDim.y;
  int bz2 = s / gridDim.y;
  dev_gemm(A, Wt + (size_t)bz2 * wtz, bias + bz2 * bz, C + (size_t)bz2 * cz,
           M, N, K, relu, by * 128, bx * 128, L);
}

__global__ __launch_bounds__(1024) void k_gemm_sk(const bfu* __restrict__ A,
                                                  const bfu* __restrict__ Wt,
                                                  float* __restrict__ Pf,
                                                  int M, int N, int K, int ksplit) {
  __shared__ GemmLds L;
  int nwg = gridDim.x * gridDim.y * gridDim.z;
  int flat = blockIdx.x + gridDim.x * (blockIdx.y + gridDim.y * blockIdx.z);
  int s = xcd_swz(flat, nwg);
  int bx = s % gridDim.x; s /= gridDim.x;
  int by = s % gridDim.y;
  int z = s / gridDim.y;
  int Kc = K / ksplit;
  dev_gemm_sk(A, Wt, Pf + (size_t)z * M * N, M, N, K, z * Kc, z * Kc + Kc,
              by * 128, bx * 128, L);
}

__global__ __launch_bounds__(512) void k_attn_mfma(const bfu* __restrict__ Q, int qs,
                                                   const bfu* __restrict__ Km,
                                                   const bfu* __restrict__ Vm, int kvs,
                                                   bfu* __restrict__ O,
                                                   int Sq, int Sk) {
  __shared__ AttnLds L;
  int nwg = gridDim.x * gridDim.y * gridDim.z;
  int flat = blockIdx.x + gridDim.x * (blockIdx.y + gridDim.y * blockIdx.z);
  int s = xcd_swz(flat, nwg);
  int qblk = s % gridDim.x; s /= gridDim.x;
  int h = s % gridDim.y;
  int b = s / gridDim.y;
  dev_attn(Q, qs, Km, Vm, kvs, O, Sq, Sk, qblk, h, b, L);
}

__global__ __launch_bounds__(256) void k_ln_red(const float* __restrict__ A,
                                                const float* __restrict__ P,
                                                int nsplit, size_t pz,
                                                const float* __restrict__ bias,
                                                const float* __restrict__ g,
                                                const float* __restrict__ be,
                                                float* __restrict__ of,
                                                bfu* __restrict__ ob,
                                                const float* __restrict__ add2,
                                                int qe_mode,
                                                float* __restrict__ of2,
                                                bfu* __restrict__ ob2,
                                                int rows) {
  dev_ln_red(A, P, nsplit, pz, bias, g, be, of, ob, add2, qe_mode, of2, ob2,
             rows, blockIdx.x);
}

__global__ __launch_bounds__(256) void k_transpose2(const float* __restrict__ s0,
                                                    const float* __restrict__ s1,
                                                    float* __restrict__ d0,
                                                    float* __restrict__ d1) {
  __shared__ float tile[32][33];
  int zz = blockIdx.z;
  const float* in = (zz < 4) ? s0 : s1;
  float* out = (zz < 4) ? d0 : d1;
  int b = zz & 3;
  int c0 = blockIdx.x * 32, s0i = blockIdx.y * 32;
  int tx = threadIdx.x, ty = threadIdx.y;
  for (int i = ty; i < 32; i += 8)
    tile[i][tx] = in[((size_t)(b * 512 + c0 + i)) * 1024 + s0i + tx];
  __syncthreads();
  for (int i = ty; i < 32; i += 8)
    out[((size_t)(b * 1024 + s0i + i)) * 512 + c0 + tx] = tile[tx][i];
}

__global__ __launch_bounds__(256) void k_wt3(const float* __restrict__ s0,
                                             const float* __restrict__ s1,
                                             const float* __restrict__ s2,
                                             bfu* __restrict__ dst,
                                             int K, int N, int per) {
  __shared__ bfu tile[32][33];
  int g = blockIdx.z;
  const float* sb = (g < per) ? s0 : (g < 2 * per) ? s1 : s2;
  int gl = (g < per) ? g : (g < 2 * per) ? (g - per) : (g - 2 * per);
  const float* s = sb + (size_t)gl * (size_t)K * N;
  bfu* d = dst + (size_t)g * (size_t)K * N;
  int n0 = blockIdx.x * 32, k0 = blockIdx.y * 32;
  int tx = threadIdx.x, ty = threadIdx.y;
  for (int i = ty; i < 32; i += 8)
    tile[i][tx] = f2bf(s[(size_t)(k0 + i) * N + n0 + tx]);
  __syncthreads();
  for (int i = ty; i < 32; i += 8)
    d[(size_t)(n0 + i) * K + k0 + tx] = tile[tx][i];
}

__global__ void k_add_dual(const float* __restrict__ a, const float* __restrict__ b,
                           float* __restrict__ of, bfu* __restrict__ ob, int n4) {
  int i = blockIdx.x * blockDim.x + threadIdx.x;
  if (i >= n4) return;
  float4 x = ((const float4*)a)[i];
  float4 y = ((const float4*)b)[i];
  float4 r = make_float4(x.x + y.x, x.y + y.y, x.z + y.z, x.w + y.w);
  ((float4*)of)[i] = r;
  ((ushort4*)ob)[i] = make_ushort4(f2bf(r.x), f2bf(r.y), f2bf(r.z), f2bf(r.w));
}

__global__ void k_qe0(const float* __restrict__ qe, float* __restrict__ of,
                      bfu* __restrict__ ob) {
  int i = blockIdx.x * blockDim.x + threadIdx.x;
  if (i >= 51200) return;
  int row = i >> 7;
  int q = row % 100;
  int c4 = i & 127;
  float4 y = ((const float4*)qe)[q * 128 + c4];
  ((float4*)of)[i] = y;
  ((ushort4*)ob)[i] = make_ushort4(f2bf(y.x), f2bf(y.y), f2bf(y.z), f2bf(y.w));
}

// ---------------------------------------------------------------------------

extern "C" void kernel_launch(void* const* d_in, const int* in_sizes, int n_in,
                              void* d_out, int out_size, void* d_ws, size_t ws_size,
                              hipStream_t stream) {
  const float* src         = (const float*)d_in[0];
  const float* query_embed = (const float*)d_in[1];
  const float* pos_embed   = (const float*)d_in[2];
  const float* enc_attn_w  = (const float*)d_in[3];
  const float* enc_attn_b  = (const float*)d_in[4];
  const float* enc_w1      = (const float*)d_in[5];
  const float* enc_b1      = (const float*)d_in[6];
  const float* enc_w2      = (const float*)d_in[7];
  const float* enc_b2      = (const float*)d_in[8];
  const float* enc_ln_w    = (const float*)d_in[9];
  const float* enc_ln_b    = (const float*)d_in[10];
  const float* dec_sa_w    = (const float*)d_in[11];
  const float* dec_sa_b    = (const float*)d_in[12];
  const float* dec_ca_w    = (const float*)d_in[13];
  const float* dec_ca_b    = (const float*)d_in[14];
  const float* dec_w1      = (const float*)d_in[15];
  const float* dec_b1      = (const float*)d_in[16];
  const float* dec_w2      = (const float*)d_in[17];
  const float* dec_b2      = (const float*)d_in[18];
  const float* dec_ln_w    = (const float*)d_in[19];
  const float* dec_ln_b    = (const float*)d_in[20];
  float* out = (float*)d_out;

  const size_t ENC = 4UL * 1024 * 512;
  const size_t DEC = 4UL * 100 * 512;
  const size_t MAT = 512UL * 512;

  float* p = (float*)d_ws;
  float* x    = p; p += ENC;
  float* pos  = p; p += ENC;
  float* t1   = p; p += ENC;
  float* t2   = p; p += ENC;
  float* t3   = p; p += DEC;
  float* Pf   = p; p += 4 * ENC;   // split-K f32 partials

  bfu* bp = (bfu*)p;
  bfu* t1b    = bp; bp += ENC;
  bfu* t2b    = bp; bp += ENC;
  bfu* t3b    = bp; bp += DEC;
  bfu* qkvb   = bp; bp += 4096UL * 1536;
  bfu* aob    = bp; bp += ENC;
  bfu* hbb    = bp; bp += 4096UL * 2048;
  bfu* meminb = bp; bp += ENC;
  bfu* ckvb   = bp; bp += 6UL * 4096 * 1024;
  bfu* att_all_t = bp; bp += 72 * MAT;
  bfu* w1_all_t  = bp; bp += 12UL * 512 * 2048;
  bfu* w2_all_t  = bp; bp += 12UL * 2048 * 512;
  bfu* enc_att_t = att_all_t;
  bfu* dsa_t     = att_all_t + 24 * MAT;
  bfu* dca_t     = att_all_t + 48 * MAT;
  bfu* enc_w1t   = w1_all_t;
  bfu* dw1t      = w1_all_t + 6UL * 512 * 2048;
  bfu* enc_w2t   = w2_all_t;
  bfu* dw2t      = w2_all_t + 6UL * 2048 * 512;

  dim3 tb(32, 8);
  k_transpose2<<<dim3(16, 32, 8), tb, 0, stream>>>(src, pos_embed, x, pos);

  k_wt3<<<dim3(16, 16, 72), tb, 0, stream>>>(enc_attn_w, dec_sa_w, dec_ca_w,
                                             att_all_t, 512, 512, 24);
  k_wt3<<<dim3(64, 16, 12), tb, 0, stream>>>(enc_w1, dec_w1, dec_w1,
                                             w1_all_t, 512, 2048, 6);
  k_wt3<<<dim3(16, 64, 12), tb, 0, stream>>>(enc_w2, dec_w2, dec_w2,
                                             w2_all_t, 2048, 512, 6);

  // ----------------------------- encoder ----------------------------------
  k_add_dual<<<2048, 256, 0, stream>>>(x, pos, t1, t1b, (int)(ENC / 4));
  for (int l = 0; l < 6; ++l) {
    const bfu* awt = enc_att_t + (size_t)l * 4 * MAT;
    const float* ab = enc_attn_b + (size_t)l * 2048;
    k_gemm_bf<<<dim3(12, 32), 1024, 0, stream>>>(t1b, awt, ab,
                                                 qkvb, 4096, 1536, 512, 0, 0, 0, 0);
    k_attn_mfma<<<dim3(8, 8, 4), 512, 0, stream>>>(qkvb, 1536, qkvb + 512, qkvb + 1024, 1536,
                                                   aob, 1024, 1024);
    k_gemm_sk<<<dim3(4, 32, 2), 1024, 0, stream>>>(aob, awt + 3 * MAT, Pf,
                                                   4096, 512, 512, 2);
    k_ln_red<<<1024, 256, 0, stream>>>(t1, Pf, 2, ENC, ab + 1536,
                                       enc_ln_w + (size_t)(l * 2 + 0) * 512,
                                       enc_ln_b + (size_t)(l * 2 + 0) * 512,
                                       t2, t2b, (const float*)nullptr, 0,
                                       (float*)nullptr, (bfu*)nullptr, 4096);
    k_gemm_bf<<<dim3(16, 32), 1024, 0, stream>>>(t2b, enc_w1t + (size_t)l * 512 * 2048,
                                                 enc_b1 + (size_t)l * 2048, hbb,
                                                 4096, 2048, 512, 1, 0, 0, 0);
    k_gemm_sk<<<dim3(4, 32, 4), 1024, 0, stream>>>(hbb, enc_w2t + (size_t)l * 2048 * 512, Pf,
                                                   4096, 512, 2048, 4);
    if (l < 5) {
      k_ln_red<<<1024, 256, 0, stream>>>(t2, Pf, 4, ENC, enc_b2 + (size_t)l * 512,
                                         enc_ln_w + (size_t)(l * 2 + 1) * 512,
                                         enc_ln_b + (size_t)(l * 2 + 1) * 512,
                                         (float*)nullptr, (bfu*)nullptr,
                                         pos, 0, t1, t1b, 4096);
    } else {
      k_ln_red<<<1024, 256, 0, stream>>>(t2, Pf, 4, ENC, enc_b2 + (size_t)l * 512,
                                         enc_ln_w + (size_t)(l * 2 + 1) * 512,
                                         enc_ln_b + (size_t)(l * 2 + 1) * 512,
                                         out + DEC, (bfu*)nullptr,
                                         pos, 0, (float*)nullptr, meminb, 4096);
    }
  }

  // all 6 decoder layers' cross-attn K/V projections in one dispatch
  k_gemm_bf<<<dim3(8, 32, 6), 1024, 0, stream>>>(meminb, dca_t + MAT, dec_ca_b + 512,
                                                 ckvb, 4096, 1024, 512, 0,
                                                 4 * MAT, 4096UL * 1024, 2048);

  // ----------------------------- decoder ----------------------------------
  k_qe0<<<200, 256, 0, stream>>>(query_embed, t1, t1b);
  for (int l = 0; l < 6; ++l) {
    const bfu* swt = dsa_t + (size_t)l * 4 * MAT;
    const bfu* cwt = dca_t + (size_t)l * 4 * MAT;
    const float* sb = dec_sa_b + (size_t)l * 2048;
    const float* cb = dec_ca_b + (size_t)l * 2048;
    // self-attention
    k_gemm_bf<<<dim3(12, 4), 1024, 0, stream>>>(t1b, swt, sb,
                                                qkvb, 400, 1536, 512, 0, 0, 0, 0);
    k_attn_mfma<<<dim3(1, 8, 4), 512, 0, stream>>>(qkvb, 1536, qkvb + 512, qkvb + 1024, 1536,
                                                   aob, 100, 100);
    k_gemm_sk<<<dim3(4, 4, 2), 1024, 0, stream>>>(aob, swt + 3 * MAT, Pf,
                                                  400, 512, 512, 2);
    k_ln_red<<<100, 256, 0, stream>>>(t1, Pf, 2, 400UL * 512, sb + 1536,
                                      dec_ln_w + (size_t)(l * 3 + 0) * 512,
                                      dec_ln_b + (size_t)(l * 3 + 0) * 512,
                                      t2, t2b, (const float*)nullptr, 0,
                                      (float*)nullptr, (bfu*)nullptr, 400);
    // cross-attention
    k_gemm_bf<<<dim3(4, 4), 1024, 0, stream>>>(t2b, cwt, cb,
                                               qkvb, 400, 512, 512, 0, 0, 0, 0);
    k_attn_mfma<<<dim3(1, 8, 4), 512, 0, stream>>>(qkvb, 512,
                                                   ckvb + (size_t)l * 4096 * 1024,
                                                   ckvb + (size_t)l * 4096 * 1024 + 512, 1024,
                                                   aob, 100, 1024);
    k_gemm_sk<<<dim3(4, 4, 2), 1024, 0, stream>>>(aob, cwt + 3 * MAT, Pf,
                                                  400, 512, 512, 2);
    k_ln_red<<<100, 256, 0, stream>>>(t2, Pf, 2, 400UL * 512, cb + 1536,
                                      dec_ln_w + (size_t)(l * 3 + 1) * 512,
                                      dec_ln_b + (size_t)(l * 3 + 1) * 512,
                                      t3, t3b, (const float*)nullptr, 0,
                                      (float*)nullptr, (bfu*)nullptr, 400);
    // ffn
    k_gemm_bf<<<dim3(16, 4), 1024, 0, stream>>>(t3b, dw1t + (size_t)l * 512 * 2048,
                                                dec_b1 + (size_t)l * 2048, hbb,
                                                400, 2048, 512, 1, 0, 0, 0);
    k_gemm_sk<<<dim3(4, 4, 4), 1024, 0, stream>>>(hbb, dw2t + (size_t)l * 2048 * 512, Pf,
                                                  400, 512, 2048, 4);
    if (l < 5) {
      k_ln_red<<<100, 256, 0, stream>>>(t3, Pf, 4, 400UL * 512, dec_b2 + (size_t)l * 512,
                                        dec_ln_w + (size_t)(l * 3 + 2) * 512,
                                        dec_ln_b + (size_t)(l * 3 + 2) * 512,
                                        (float*)nullptr, (bfu*)nullptr,
                                        query_embed, 1, t1, t1b, 400);
    } else {
      k_ln_red<<<100, 256, 0, stream>>>(t3, Pf, 4, 400UL * 512, dec_b2 + (size_t)l * 512,
                                        dec_ln_w + (size_t)(l * 3 + 2) * 512,
                                        dec_ln_b + (size_t)(l * 3 + 2) * 512,
                                        out, (bfu*)nullptr, (const float*)nullptr, 0,
                                        (float*)nullptr, (bfu*)nullptr, 400);
    }
  }
}

// Round 22
// 1643.694 us; speedup vs baseline: 1.1654x; 1.0228x over previous
//
#include <hip/hip_runtime.h>
#include <math.h>

// ---------------------------------------------------------------------------
// DETR-style transformer. bf16 MFMA GEMMs (1024-thread/16-wave blocks,
// global_load_lds, BK=64 2-phase dbuf, XOR-swizzled LDS, XCD block swizzle)
// + bf16 MFMA flash attention (512-thread/8-wave, 128 q-rows, KVBLK=128,
// setprio). Split-K GEMMs -> bf16 partials; k_ln_red fuses
// reduce+bias+residual+LN+re-add.
// B=4, S=1024, NQ=100, D=512, H=8, dk=64, FF=2048, L=6
// ---------------------------------------------------------------------------

typedef unsigned short bfu;
typedef unsigned int u32;
typedef __bf16 bf8v __attribute__((ext_vector_type(8)));
typedef float f32x4 __attribute__((ext_vector_type(4)));

__device__ inline bfu f2bf(float f) {
  union { float f; u32 u; } v; v.f = f;
  u32 u = v.u;
  u32 r = (u + 0x7fffu + ((u >> 16) & 1u)) >> 16;
  return (bfu)r;
}
__device__ inline float bflo(u32 u) { return __uint_as_float(u << 16); }

typedef const __attribute__((address_space(1))) u32 gas_t;
typedef __attribute__((address_space(3))) u32 las_t;
__device__ __forceinline__ void gl16(const void* g, void* l) {
  __builtin_amdgcn_global_load_lds((gas_t*)g, (las_t*)l, 16, 0, 0);
}

// bijective XCD swizzle (m204): consecutive logical tiles -> same XCD chunk
__device__ __forceinline__ int xcd_swz(int flat, int nwg) {
  int q = nwg >> 3, r = nwg & 7;
  int xcd = flat & 7, idx = flat >> 3;
  return (xcd < r ? xcd * (q + 1) : r * (q + 1) + (xcd - r) * q) + idx;
}

struct GemmLds { bfu As[2][128][64]; bfu Bs[2][128][64]; };      // 64 KB
struct AttnLds { bfu Ks[128][72]; bfu Vt[64][136]; bfu Sm[8][16][136]; };  // ~70 KB

// ---------------- device GEMM body: 16 waves, BK=64, gl_lds, 2-phase dbuf --
__device__ void dev_gemm(const bfu* __restrict__ A, const bfu* __restrict__ Wt,
                         const float* __restrict__ bias, bfu* __restrict__ C,
                         int M, int N, int K, int relu, int bm, int bn,
                         GemmLds& L) {
  int t = threadIdx.x;
  int wave = t >> 6, lane = t & 63;
  int wm = wave >> 1, wn = wave & 1;
  int l15 = lane & 15, l4 = lane >> 4;
  f32x4 acc[4];
  f32x4 zz = {0.f, 0.f, 0.f, 0.f};
#pragma unroll
  for (int ni = 0; ni < 4; ++ni) acc[ni] = zz;

  auto stage = [&](int buf, int k0) {
    int c = t;                        // 0..1023 chunks of 16B
    int row = c >> 3, kg = c & 7;
    int sc = kg ^ (row & 7);
    if (bm + row < M)
      gl16(A + (size_t)(bm + row) * K + k0 + sc * 8, &L.As[buf][row][kg * 8]);
    gl16(Wt + (size_t)(bn + row) * K + k0 + sc * 8, &L.Bs[buf][row][kg * 8]);
  };
  stage(0, 0);
  int cur = 0;
  for (int k0 = 0; k0 < K; k0 += 64) {
    __syncthreads();
    if (k0 + 64 < K) stage(cur ^ 1, k0 + 64);
#pragma unroll
    for (int kc = 0; kc < 2; ++kc) {
      int rowA = wm * 16 + l15;
      bf8v av = *(const bf8v*)&L.As[cur][rowA][((kc * 4 + l4) ^ (rowA & 7)) * 8];
      bf8v bv[4];
#pragma unroll
      for (int ni = 0; ni < 4; ++ni) {
        int row = wn * 64 + ni * 16 + l15;
        bv[ni] = *(const bf8v*)&L.Bs[cur][row][((kc * 4 + l4) ^ (row & 7)) * 8];
      }
#pragma unroll
      for (int ni = 0; ni < 4; ++ni)
        acc[ni] = __builtin_amdgcn_mfma_f32_16x16x32_bf16(av, bv[ni], acc[ni], 0, 0, 0);
    }
    cur ^= 1;
  }

  int row0 = bm + wm * 16 + l4 * 4;
#pragma unroll
  for (int ni = 0; ni < 4; ++ni) {
    int col = bn + wn * 64 + ni * 16 + l15;
    float bb = bias[col];
#pragma unroll
    for (int r = 0; r < 4; ++r) {
      int row = row0 + r;
      if (row < M) {
        float v = acc[ni][r] + bb;
        if (relu) v = fmaxf(v, 0.f);
        C[(size_t)row * N + col] = f2bf(v);
      }
    }
  }
}

// ---------------- device split-K GEMM -> bf16 partials (16 waves) ----------
__device__ void dev_gemm_sk(const bfu* __restrict__ A, const bfu* __restrict__ Wt,
                            bfu* __restrict__ Pf, int M, int N, int K,
                            int kbeg, int kend, int bm, int bn, GemmLds& L) {
  int t = threadIdx.x;
  int wave = t >> 6, lane = t & 63;
  int wm = wave >> 1, wn = wave & 1;
  int l15 = lane & 15, l4 = lane >> 4;
  f32x4 acc[4];
  f32x4 zz = {0.f, 0.f, 0.f, 0.f};
#pragma unroll
  for (int ni = 0; ni < 4; ++ni) acc[ni] = zz;

  auto stage = [&](int buf, int k0) {
    int c = t;
    int row = c >> 3, kg = c & 7;
    int sc = kg ^ (row & 7);
    if (bm + row < M)
      gl16(A + (size_t)(bm + row) * K + k0 + sc * 8, &L.As[buf][row][kg * 8]);
    gl16(Wt + (size_t)(bn + row) * K + k0 + sc * 8, &L.Bs[buf][row][kg * 8]);
  };
  stage(0, kbeg);
  int cur = 0;
  for (int k0 = kbeg; k0 < kend; k0 += 64) {
    __syncthreads();
    if (k0 + 64 < kend) stage(cur ^ 1, k0 + 64);
#pragma unroll
    for (int kc = 0; kc < 2; ++kc) {
      int rowA = wm * 16 + l15;
      bf8v av = *(const bf8v*)&L.As[cur][rowA][((kc * 4 + l4) ^ (rowA & 7)) * 8];
      bf8v bv[4];
#pragma unroll
      for (int ni = 0; ni < 4; ++ni) {
        int row = wn * 64 + ni * 16 + l15;
        bv[ni] = *(const bf8v*)&L.Bs[cur][row][((kc * 4 + l4) ^ (row & 7)) * 8];
      }
#pragma unroll
      for (int ni = 0; ni < 4; ++ni)
        acc[ni] = __builtin_amdgcn_mfma_f32_16x16x32_bf16(av, bv[ni], acc[ni], 0, 0, 0);
    }
    cur ^= 1;
  }

  int row0 = bm + wm * 16 + l4 * 4;
#pragma unroll
  for (int ni = 0; ni < 4; ++ni) {
    int col = bn + wn * 64 + ni * 16 + l15;
#pragma unroll
    for (int r = 0; r < 4; ++r) {
      int row = row0 + r;
      if (row < M) Pf[(size_t)row * N + col] = f2bf(acc[ni][r]);
    }
  }
}

// ---------------- device flash attention: 8 waves, 128 q-rows, KVBLK=128 ---
__device__ void dev_attn(const bfu* __restrict__ Q, int qs,
                         const bfu* __restrict__ Km,
                         const bfu* __restrict__ Vm, int kvs,
                         bfu* __restrict__ O, int Sq, int Sk,
                         int qblk, int h, int b, AttnLds& L) {
  const float scale = 0.125f;
  int q0 = qblk * 128;
  int t = threadIdx.x;
  int wave = t >> 6, lane = t & 63;
  int l15 = lane & 15, l4 = lane >> 4;
  int hoff = h * 64;

  uint4 uq0 = {0u, 0u, 0u, 0u}, uq1 = {0u, 0u, 0u, 0u};
  {
    int qrow = q0 + wave * 16 + l15;
    if (qrow < Sq) {
      const bfu* qp = Q + (size_t)(b * Sq + qrow) * qs + hoff + l4 * 8;
      uq0 = *(const uint4*)qp;
      uq1 = *(const uint4*)(qp + 32);
    }
  }
  bf8v qf0 = *(bf8v*)&uq0, qf1 = *(bf8v*)&uq1;

  float m_[4] = {-1e30f, -1e30f, -1e30f, -1e30f};
  float l_[4] = {0.f, 0.f, 0.f, 0.f};
  f32x4 oacc[4];
  f32x4 zz = {0.f, 0.f, 0.f, 0.f};
#pragma unroll
  for (int n = 0; n < 4; ++n) oacc[n] = zz;

  uint4 ruk[2], ruv[2];
  const uint4 uz = {0u, 0u, 0u, 0u};
  auto load_kv = [&](int k0) {
#pragma unroll
    for (int i = 0; i < 2; ++i) {
      int e = t + i * 512;
      int rk = e >> 3, cg = e & 7;
      ruk[i] = uz;
      if (k0 + rk < Sk)
        ruk[i] = *(const uint4*)(Km + (size_t)(b * Sk + k0 + rk) * kvs + hoff + cg * 8);
      int kv = e & 127, dg = e >> 7;
      ruv[i] = uz;
      if (k0 + kv < Sk)
        ruv[i] = *(const uint4*)(Vm + (size_t)(b * Sk + k0 + kv) * kvs + hoff + dg * 8);
    }
  };
  load_kv(0);

  for (int k0 = 0; k0 < Sk; k0 += 128) {
#pragma unroll
    for (int i = 0; i < 2; ++i) {
      int e = t + i * 512;
      int rk = e >> 3, cg = e & 7;
      *(uint4*)&L.Ks[rk][cg * 8] = ruk[i];
      int kv = e & 127, dg = e >> 7;
      bfu vv[8];
      *(uint4*)vv = ruv[i];
#pragma unroll
      for (int j = 0; j < 8; ++j) L.Vt[dg * 8 + j][kv] = vv[j];
    }
    __syncthreads();
    if (k0 + 128 < Sk) load_kv(k0 + 128);

    f32x4 s4[8];
    __builtin_amdgcn_s_setprio(1);
#pragma unroll
    for (int tt = 0; tt < 8; ++tt) {
      bf8v kf0 = *(const bf8v*)&L.Ks[tt * 16 + l15][l4 * 8];
      bf8v kf1 = *(const bf8v*)&L.Ks[tt * 16 + l15][32 + l4 * 8];
      f32x4 a = zz;
      a = __builtin_amdgcn_mfma_f32_16x16x32_bf16(qf0, kf0, a, 0, 0, 0);
      a = __builtin_amdgcn_mfma_f32_16x16x32_bf16(qf1, kf1, a, 0, 0, 0);
      s4[tt] = a;
    }
    __builtin_amdgcn_s_setprio(0);

    bool full = (k0 + 128 <= Sk);
    float f_[4];
#pragma unroll
    for (int r = 0; r < 4; ++r) {
      float sv[8];
      float mx = -1e30f;
      if (full) {
#pragma unroll
        for (int tt = 0; tt < 8; ++tt) {
          float s = s4[tt][r] * scale;
          sv[tt] = s;
          mx = fmaxf(mx, s);
        }
      } else {
#pragma unroll
        for (int tt = 0; tt < 8; ++tt) {
          float s = s4[tt][r] * scale;
          s = (k0 + tt * 16 + l15 < Sk) ? s : -1e30f;
          sv[tt] = s;
          mx = fmaxf(mx, s);
        }
      }
#pragma unroll
      for (int off = 1; off < 16; off <<= 1) mx = fmaxf(mx, __shfl_xor(mx, off));
      float nm = fmaxf(m_[r], mx);
      float f = __expf(m_[r] - nm);
      float ps = 0.f;
#pragma unroll
      for (int tt = 0; tt < 8; ++tt) {
        float p = __expf(sv[tt] - nm);
        ps += p;
        L.Sm[wave][l4 * 4 + r][tt * 16 + l15] = f2bf(p);
      }
#pragma unroll
      for (int off = 1; off < 16; off <<= 1) ps += __shfl_xor(ps, off);
      l_[r] = l_[r] * f + ps;
      m_[r] = nm;
      f_[r] = f;
    }
#pragma unroll
    for (int n = 0; n < 4; ++n)
#pragma unroll
      for (int r = 0; r < 4; ++r) oacc[n][r] *= f_[r];

    __builtin_amdgcn_s_setprio(1);
#pragma unroll
    for (int h2 = 0; h2 < 2; ++h2) {
      bf8v p0 = *(const bf8v*)&L.Sm[wave][l15][h2 * 64 + l4 * 8];
      bf8v p1 = *(const bf8v*)&L.Sm[wave][l15][h2 * 64 + 32 + l4 * 8];
#pragma unroll
      for (int n = 0; n < 4; ++n) {
        bf8v v0 = *(const bf8v*)&L.Vt[n * 16 + l15][h2 * 64 + l4 * 8];
        bf8v v1 = *(const bf8v*)&L.Vt[n * 16 + l15][h2 * 64 + 32 + l4 * 8];
        oacc[n] = __builtin_amdgcn_mfma_f32_16x16x32_bf16(p0, v0, oacc[n], 0, 0, 0);
        oacc[n] = __builtin_amdgcn_mfma_f32_16x16x32_bf16(p1, v1, oacc[n], 0, 0, 0);
      }
    }
    __builtin_amdgcn_s_setprio(0);
    __syncthreads();
  }

#pragma unroll
  for (int r = 0; r < 4; ++r) {
    int row = q0 + wave * 16 + l4 * 4 + r;
    if (row < Sq) {
      float inv = 1.f / l_[r];
#pragma unroll
      for (int n = 0; n < 4; ++n)
        O[(size_t)(b * Sq + row) * 512 + hoff + n * 16 + l15] = f2bf(oacc[n][r] * inv);
    }
  }
}

// ---------------- device LN(A + sum_z bf16 P[z] + bias), fused epilogues ---
__device__ void dev_ln_red(const float* __restrict__ A, const bfu* __restrict__ P,
                           int nsplit, size_t pz, const float* __restrict__ bias,
                           const float* __restrict__ g, const float* __restrict__ be,
                           float* __restrict__ of, bfu* __restrict__ ob,
                           const float* __restrict__ add2, int qe_mode,
                           float* __restrict__ of2, bfu* __restrict__ ob2,
                           int rows, int tile) {
  int row = tile * 4 + (threadIdx.x >> 6);
  int lane = threadIdx.x & 63;
  if (row < rows) {
    const float* pa = A + (size_t)row * 512;
    float v[8];
    float s = 0.f, s2 = 0.f;
#pragma unroll
    for (int j = 0; j < 8; ++j) {
      int c = lane + j * 64;
      float x = pa[c] + bias[c];
      for (int z = 0; z < nsplit; ++z) x += bflo((u32)P[z * pz + (size_t)row * 512 + c]);
      v[j] = x; s += x; s2 += x * x;
    }
#pragma unroll
    for (int off = 32; off > 0; off >>= 1) {
      s += __shfl_xor(s, off);
      s2 += __shfl_xor(s2, off);
    }
    float mean = s * (1.f / 512.f);
    float var = s2 * (1.f / 512.f) - mean * mean;
    float r = rsqrtf(var + 1e-5f);
    int arow = qe_mode ? (row % 100) : row;
#pragma unroll
    for (int j = 0; j < 8; ++j) {
      int c = lane + j * 64;
      float o = (v[j] - mean) * r * g[c] + be[c];
      if (of) of[(size_t)row * 512 + c] = o;
      if (ob) ob[(size_t)row * 512 + c] = f2bf(o);
      if (add2) {
        float o2 = o + add2[(size_t)arow * 512 + c];
        if (of2) of2[(size_t)row * 512 + c] = o2;
        if (ob2) ob2[(size_t)row * 512 + c] = f2bf(o2);
      }
    }
  }
}

// ---------------- standalone kernels ----------------------------------------
__global__ __launch_bounds__(1024) void k_gemm_bf(const bfu* __restrict__ A,
                                                  const bfu* __restrict__ Wt,
                                                  const float* __restrict__ bias,
                                                  bfu* __restrict__ C,
                                                  int M, int N, int K, int relu,
                                                  size_t wtz, size_t cz, int bz) {
  __shared__ GemmLds L;
  int nwg = gridDim.x * gridDim.y * gridDim.z;
  int flat = blockIdx.x + gridDim.x * (blockIdx.y + gridDim.y * blockIdx.z);
  int s = xcd_swz(flat, nwg);
  int bx = s % gridDim.x; s /= gridDim.x;
  int by = s % gridDim.y;
  int bz2 = s / gridDim.y;
  dev_gemm(A, Wt + (size_t)bz2 * wtz, bias + bz2 * bz, C + (size_t)bz2 * cz,
           M, N, K, relu, by * 128, bx * 128, L);
}

__global__ __launch_bounds__(1024) void k_gemm_sk(const bfu* __restrict__ A,
                                                  const bfu* __restrict__ Wt,
                                                  bfu* __restrict__ Pf,
                                                  int M, int N, int K, int ksplit) {
  __shared__ GemmLds L;
  int nwg = gridDim.x * gridDim.y * gridDim.z;
  int flat = blockIdx.x + gridDim.x * (blockIdx.y + gridDim.y * blockIdx.z);
  int s = xcd_swz(flat, nwg);
  int bx = s % gridDim.x; s /= gridDim.x;
  int by = s % gridDim.y;
  int z = s / gridDim.y;
  int Kc = K / ksplit;
  dev_gemm_sk(A, Wt, Pf + (size_t)z * M * N, M, N, K, z * Kc, z * Kc + Kc,
              by * 128, bx * 128, L);
}

__global__ __launch_bounds__(512) void k_attn_mfma(const bfu* __restrict__ Q, int qs,
                                                   const bfu* __restrict__ Km,
                                                   const bfu* __restrict__ Vm, int kvs,
                                                   bfu* __restrict__ O,
                                                   int Sq, int Sk) {
  __shared__ AttnLds L;
  int nwg = gridDim.x * gridDim.y * gridDim.z;
  int flat = blockIdx.x + gridDim.x * (blockIdx.y + gridDim.y * blockIdx.z);
  int s = xcd_swz(flat, nwg);
  int qblk = s % gridDim.x; s /= gridDim.x;
  int h = s % gridDim.y;
  int b = s / gridDim.y;
  dev_attn(Q, qs, Km, Vm, kvs, O, Sq, Sk, qblk, h, b, L);
}

__global__ __launch_bounds__(256) void k_ln_red(const float* __restrict__ A,
                                                const bfu* __restrict__ P,
                                                int nsplit, size_t pz,
                                                const float* __restrict__ bias,
                                                const float* __restrict__ g,
                                                const float* __restrict__ be,
                                                float* __restrict__ of,
                                                bfu* __restrict__ ob,
                                                const float* __restrict__ add2,
                                                int qe_mode,
                                                float* __restrict__ of2,
                                                bfu* __restrict__ ob2,
                                                int rows) {
  dev_ln_red(A, P, nsplit, pz, bias, g, be, of, ob, add2, qe_mode, of2, ob2,
             rows, blockIdx.x);
}

__global__ __launch_bounds__(256) void k_transpose2(const float* __restrict__ s0,
                                                    const float* __restrict__ s1,
                                                    float* __restrict__ d0,
                                                    float* __restrict__ d1) {
  __shared__ float tile[32][33];
  int zz = blockIdx.z;
  const float* in = (zz < 4) ? s0 : s1;
  float* out = (zz < 4) ? d0 : d1;
  int b = zz & 3;
  int c0 = blockIdx.x * 32, s0i = blockIdx.y * 32;
  int tx = threadIdx.x, ty = threadIdx.y;
  for (int i = ty; i < 32; i += 8)
    tile[i][tx] = in[((size_t)(b * 512 + c0 + i)) * 1024 + s0i + tx];
  __syncthreads();
  for (int i = ty; i < 32; i += 8)
    out[((size_t)(b * 1024 + s0i + i)) * 512 + c0 + tx] = tile[tx][i];
}

__global__ __launch_bounds__(256) void k_wt3(const float* __restrict__ s0,
                                             const float* __restrict__ s1,
                                             const float* __restrict__ s2,
                                             bfu* __restrict__ dst,
                                             int K, int N, int per) {
  __shared__ bfu tile[32][33];
  int g = blockIdx.z;
  const float* sb = (g < per) ? s0 : (g < 2 * per) ? s1 : s2;
  int gl = (g < per) ? g : (g < 2 * per) ? (g - per) : (g - 2 * per);
  const float* s = sb + (size_t)gl * (size_t)K * N;
  bfu* d = dst + (size_t)g * (size_t)K * N;
  int n0 = blockIdx.x * 32, k0 = blockIdx.y * 32;
  int tx = threadIdx.x, ty = threadIdx.y;
  for (int i = ty; i < 32; i += 8)
    tile[i][tx] = f2bf(s[(size_t)(k0 + i) * N + n0 + tx]);
  __syncthreads();
  for (int i = ty; i < 32; i += 8)
    d[(size_t)(n0 + i) * K + k0 + tx] = tile[tx][i];
}

__global__ void k_add_dual(const float* __restrict__ a, const float* __restrict__ b,
                           float* __restrict__ of, bfu* __restrict__ ob, int n4) {
  int i = blockIdx.x * blockDim.x + threadIdx.x;
  if (i >= n4) return;
  float4 x = ((const float4*)a)[i];
  float4 y = ((const float4*)b)[i];
  float4 r = make_float4(x.x + y.x, x.y + y.y, x.z + y.z, x.w + y.w);
  ((float4*)of)[i] = r;
  ((ushort4*)ob)[i] = make_ushort4(f2bf(r.x), f2bf(r.y), f2bf(r.z), f2bf(r.w));
}

__global__ void k_qe0(const float* __restrict__ qe, float* __restrict__ of,
                      bfu* __restrict__ ob) {
  int i = blockIdx.x * blockDim.x + threadIdx.x;
  if (i >= 51200) return;
  int row = i >> 7;
  int q = row % 100;
  int c4 = i & 127;
  float4 y = ((const float4*)qe)[q * 128 + c4];
  ((float4*)of)[i] = y;
  ((ushort4*)ob)[i] = make_ushort4(f2bf(y.x), f2bf(y.y), f2bf(y.z), f2bf(y.w));
}

// ---------------------------------------------------------------------------

extern "C" void kernel_launch(void* const* d_in, const int* in_sizes, int n_in,
                              void* d_out, int out_size, void* d_ws, size_t ws_size,
                              hipStream_t stream) {
  const float* src         = (const float*)d_in[0];
  const float* query_embed = (const float*)d_in[1];
  const float* pos_embed   = (const float*)d_in[2];
  const float* enc_attn_w  = (const float*)d_in[3];
  const float* enc_attn_b  = (const float*)d_in[4];
  const float* enc_w1      = (const float*)d_in[5];
  const float* enc_b1      = (const float*)d_in[6];
  const float* enc_w2      = (const float*)d_in[7];
  const float* enc_b2      = (const float*)d_in[8];
  const float* enc_ln_w    = (const float*)d_in[9];
  const float* enc_ln_b    = (const float*)d_in[10];
  const float* dec_sa_w    = (const float*)d_in[11];
  const float* dec_sa_b    = (const float*)d_in[12];
  const float* dec_ca_w    = (const float*)d_in[13];
  const float* dec_ca_b    = (const float*)d_in[14];
  const float* dec_w1      = (const float*)d_in[15];
  const float* dec_b1      = (const float*)d_in[16];
  const float* dec_w2      = (const float*)d_in[17];
  const float* dec_b2      = (const float*)d_in[18];
  const float* dec_ln_w    = (const float*)d_in[19];
  const float* dec_ln_b    = (const float*)d_in[20];
  float* out = (float*)d_out;

  const size_t ENC = 4UL * 1024 * 512;
  const size_t DEC = 4UL * 100 * 512;
  const size_t MAT = 512UL * 512;

  float* p = (float*)d_ws;
  float* x    = p; p += ENC;
  float* pos  = p; p += ENC;
  float* t1   = p; p += ENC;
  float* t2   = p; p += ENC;
  float* t3   = p; p += DEC;
  bfu* Pf     = (bfu*)p; p += 2 * ENC;   // split-K bf16 partials (4 x ENC bfu)

  bfu* bp = (bfu*)p;
  bfu* t1b    = bp; bp += ENC;
  bfu* t2b    = bp; bp += ENC;
  bfu* t3b    = bp; bp += DEC;
  bfu* qkvb   = bp; bp += 4096UL * 1536;
  bfu* aob    = bp; bp += ENC;
  bfu* hbb    = bp; bp += 4096UL * 2048;
  bfu* meminb = bp; bp += ENC;
  bfu* ckvb   = bp; bp += 6UL * 4096 * 1024;
  bfu* att_all_t = bp; bp += 72 * MAT;
  bfu* w1_all_t  = bp; bp += 12UL * 512 * 2048;
  bfu* w2_all_t  = bp; bp += 12UL * 2048 * 512;
  bfu* enc_att_t = att_all_t;
  bfu* dsa_t     = att_all_t + 24 * MAT;
  bfu* dca_t     = att_all_t + 48 * MAT;
  bfu* enc_w1t   = w1_all_t;
  bfu* dw1t      = w1_all_t + 6UL * 512 * 2048;
  bfu* enc_w2t   = w2_all_t;
  bfu* dw2t      = w2_all_t + 6UL * 2048 * 512;

  dim3 tb(32, 8);
  k_transpose2<<<dim3(16, 32, 8), tb, 0, stream>>>(src, pos_embed, x, pos);

  k_wt3<<<dim3(16, 16, 72), tb, 0, stream>>>(enc_attn_w, dec_sa_w, dec_ca_w,
                                             att_all_t, 512, 512, 24);
  k_wt3<<<dim3(64, 16, 12), tb, 0, stream>>>(enc_w1, dec_w1, dec_w1,
                                             w1_all_t, 512, 2048, 6);
  k_wt3<<<dim3(16, 64, 12), tb, 0, stream>>>(enc_w2, dec_w2, dec_w2,
                                             w2_all_t, 2048, 512, 6);

  // ----------------------------- encoder ----------------------------------
  k_add_dual<<<2048, 256, 0, stream>>>(x, pos, t1, t1b, (int)(ENC / 4));
  for (int l = 0; l < 6; ++l) {
    const bfu* awt = enc_att_t + (size_t)l * 4 * MAT;
    const float* ab = enc_attn_b + (size_t)l * 2048;
    k_gemm_bf<<<dim3(12, 32), 1024, 0, stream>>>(t1b, awt, ab,
                                                 qkvb, 4096, 1536, 512, 0, 0, 0, 0);
    k_attn_mfma<<<dim3(8, 8, 4), 512, 0, stream>>>(qkvb, 1536, qkvb + 512, qkvb + 1024, 1536,
                                                   aob, 1024, 1024);
    k_gemm_sk<<<dim3(4, 32, 2), 1024, 0, stream>>>(aob, awt + 3 * MAT, Pf,
                                                   4096, 512, 512, 2);
    k_ln_red<<<1024, 256, 0, stream>>>(t1, Pf, 2, ENC, ab + 1536,
                                       enc_ln_w + (size_t)(l * 2 + 0) * 512,
                                       enc_ln_b + (size_t)(l * 2 + 0) * 512,
                                       t2, t2b, (const float*)nullptr, 0,
                                       (float*)nullptr, (bfu*)nullptr, 4096);
    k_gemm_bf<<<dim3(16, 32), 1024, 0, stream>>>(t2b, enc_w1t + (size_t)l * 512 * 2048,
                                                 enc_b1 + (size_t)l * 2048, hbb,
                                                 4096, 2048, 512, 1, 0, 0, 0);
    k_gemm_sk<<<dim3(4, 32, 4), 1024, 0, stream>>>(hbb, enc_w2t + (size_t)l * 2048 * 512, Pf,
                                                   4096, 512, 2048, 4);
    if (l < 5) {
      k_ln_red<<<1024, 256, 0, stream>>>(t2, Pf, 4, ENC, enc_b2 + (size_t)l * 512,
                                         enc_ln_w + (size_t)(l * 2 + 1) * 512,
                                         enc_ln_b + (size_t)(l * 2 + 1) * 512,
                                         (float*)nullptr, (bfu*)nullptr,
                                         pos, 0, t1, t1b, 4096);
    } else {
      k_ln_red<<<1024, 256, 0, stream>>>(t2, Pf, 4, ENC, enc_b2 + (size_t)l * 512,
                                         enc_ln_w + (size_t)(l * 2 + 1) * 512,
                                         enc_ln_b + (size_t)(l * 2 + 1) * 512,
                                         out + DEC, (bfu*)nullptr,
                                         pos, 0, (float*)nullptr, meminb, 4096);
    }
  }

  // all 6 decoder layers' cross-attn K/V projections in one dispatch
  k_gemm_bf<<<dim3(8, 32, 6), 1024, 0, stream>>>(meminb, dca_t + MAT, dec_ca_b + 512,
                                                 ckvb, 4096, 1024, 512, 0,
                                                 4 * MAT, 4096UL * 1024, 2048);

  // ----------------------------- decoder ----------------------------------
  k_qe0<<<200, 256, 0, stream>>>(query_embed, t1, t1b);
  for (int l = 0; l < 6; ++l) {
    const bfu* swt = dsa_t + (size_t)l * 4 * MAT;
    const bfu* cwt = dca_t + (size_t)l * 4 * MAT;
    const float* sb = dec_sa_b + (size_t)l * 2048;
    const float* cb = dec_ca_b + (size_t)l * 2048;
    // self-attention
    k_gemm_bf<<<dim3(12, 4), 1024, 0, stream>>>(t1b, swt, sb,
                                                qkvb, 400, 1536, 512, 0, 0, 0, 0);
    k_attn_mfma<<<dim3(1, 8, 4), 512, 0, stream>>>(qkvb, 1536, qkvb + 512, qkvb + 1024, 1536,
                                                   aob, 100, 100);
    k_gemm_sk<<<dim3(4, 4, 2), 1024, 0, stream>>>(aob, swt + 3 * MAT, Pf,
                                                  400, 512, 512, 2);
    k_ln_red<<<100, 256, 0, stream>>>(t1, Pf, 2, 400UL * 512, sb + 1536,
                                      dec_ln_w + (size_t)(l * 3 + 0) * 512,
                                      dec_ln_b + (size_t)(l * 3 + 0) * 512,
                                      t2, t2b, (const float*)nullptr, 0,
                                      (float*)nullptr, (bfu*)nullptr, 400);
    // cross-attention
    k_gemm_bf<<<dim3(4, 4), 1024, 0, stream>>>(t2b, cwt, cb,
                                               qkvb, 400, 512, 512, 0, 0, 0, 0);
    k_attn_mfma<<<dim3(1, 8, 4), 512, 0, stream>>>(qkvb, 512,
                                                   ckvb + (size_t)l * 4096 * 1024,
                                                   ckvb + (size_t)l * 4096 * 1024 + 512, 1024,
                                                   aob, 100, 1024);
    k_gemm_sk<<<dim3(4, 4, 2), 1024, 0, stream>>>(aob, cwt + 3 * MAT, Pf,
                                                  400, 512, 512, 2);
    k_ln_red<<<100, 256, 0, stream>>>(t2, Pf, 2, 400UL * 512, cb + 1536,
                                      dec_ln_w + (size_t)(l * 3 + 1) * 512,
                                      dec_ln_b + (size_t)(l * 3 + 1) * 512,
                                      t3, t3b, (const float*)nullptr, 0,
                                      (float*)nullptr, (bfu*)nullptr, 400);
    // ffn
    k_gemm_bf<<<dim3(16, 4), 1024, 0, stream>>>(t3b, dw1t + (size_t)l * 512 * 2048,
                                                dec_b1 + (size_t)l * 2048, hbb,
                                                400, 2048, 512, 1, 0, 0, 0);
    k_gemm_sk<<<dim3(4, 4, 4), 1024, 0, stream>>>(hbb, dw2t + (size_t)l * 2048 * 512, Pf,
                                                  400, 512, 2048, 4);
    if (l < 5) {
      k_ln_red<<<100, 256, 0, stream>>>(t3, Pf, 4, 400UL * 512, dec_b2 + (size_t)l * 512,
                                        dec_ln_w + (size_t)(l * 3 + 2) * 512,
                                        dec_ln_b + (size_t)(l * 3 + 2) * 512,
                                        (float*)nullptr, (bfu*)nullptr,
                                        query_embed, 1, t1, t1b, 400);
    } else {
      k_ln_red<<<100, 256, 0, stream>>>(t3, Pf, 4, 400UL * 512, dec_b2 + (size_t)l * 512,
                                        dec_ln_w + (size_t)(l * 3 + 2) * 512,
                                        dec_ln_b + (size_t)(l * 3 + 2) * 512,
                                        out, (bfu*)nullptr, (const float*)nullptr, 0,
                                        (float*)nullptr, (bfu*)nullptr, 400);
    }
  }
}